// Round 2
// baseline (16678.448 us; speedup 1.0000x reference)
//
#include <hip/hip_runtime.h>
#include <hip/hip_bf16.h>
#include <cstdint>

#define NNODES 50000
#define MPAD   50048   // 782 * 64
#define NEDGES 800000
#define DIN 128
#define HID 256
#define NCLS 40
#define NBLK 3
#define EPSV 1e-5f

// ---------------- CSR build ----------------
__global__ void hist_kernel(const int* __restrict__ dst, int* __restrict__ cnt, int E) {
  int e = blockIdx.x * blockDim.x + threadIdx.x;
  if (e < E) atomicAdd(&cnt[dst[e]], 1);
}

__global__ void scan_kernel(const int* __restrict__ cnt, int* __restrict__ row_ptr,
                            float* __restrict__ inv_cnt, int N) {
  __shared__ int sums[1024];
  int t = threadIdx.x;
  int chunk = (N + 1023) >> 10;
  int beg = t * chunk;
  int end = beg + chunk; if (end > N) end = N;
  int s = 0;
  for (int i = beg; i < end; ++i) s += cnt[i];
  sums[t] = s;
  __syncthreads();
  for (int off = 1; off < 1024; off <<= 1) {
    int v = 0;
    if (t >= off) v = sums[t - off];
    __syncthreads();
    sums[t] += v;
    __syncthreads();
  }
  int run = (t == 0) ? 0 : sums[t - 1];
  for (int i = beg; i < end; ++i) {
    row_ptr[i] = run;
    int c = cnt[i];
    inv_cnt[i] = 1.0f / (float)(c > 0 ? c : 1);
    run += c;
  }
  if (t == 1023) row_ptr[N] = run;
}

__global__ void fill_kernel(const int* __restrict__ src, const int* __restrict__ dst,
                            const int* __restrict__ row_ptr, int* __restrict__ fillc,
                            int* __restrict__ col, int E) {
  int e = blockIdx.x * blockDim.x + threadIdx.x;
  if (e < E) {
    int d = dst[e];
    int pos = atomicAdd(&fillc[d], 1);
    col[row_ptr[d] + pos] = src[e];
  }
}

// ---------------- mean aggregation: one block per node ----------------
__global__ __launch_bounds__(256)
void agg_kernel(const float* __restrict__ x, float* __restrict__ out,
                const int* __restrict__ row_ptr, const int* __restrict__ col,
                const float* __restrict__ inv_cnt) {
  int n = blockIdx.x;
  int h = threadIdx.x;
  int beg = row_ptr[n], end = row_ptr[n + 1];
  float s = 0.0f;
  for (int j = beg; j < end; ++j) {
    int c = col[j];
    s += x[(long)c * HID + h];
  }
  out[(long)n * HID + h] = s * inv_cnt[n];
}

// ---------------- fold BN params: S = g*rsqrt(v+eps), T = (bl-m)*S + b ----------------
__global__ void fold_kernel(const float* __restrict__ b1l, const float* __restrict__ g1,
                            const float* __restrict__ bb1, const float* __restrict__ m1,
                            const float* __restrict__ v1,
                            const float* __restrict__ b2l, const float* __restrict__ g2,
                            const float* __restrict__ bb2, const float* __restrict__ m2,
                            const float* __restrict__ v2,
                            float* __restrict__ S1, float* __restrict__ T1,
                            float* __restrict__ S2, float* __restrict__ T2) {
  int idx = blockIdx.x * 256 + threadIdx.x;  // 0..767
  float s1 = g1[idx] * rsqrtf(v1[idx] + EPSV);
  S1[idx] = s1;
  T1[idx] = (b1l[idx] - m1[idx]) * s1 + bb1[idx];
  float s2 = g2[idx] * rsqrtf(v2[idx] + EPSV);
  S2[idx] = s2;
  T2[idx] = (b2l[idx] - m2[idx]) * s2 + bb2[idx];
}

// ---------------- fused fp32 GEMM, software-pipelined, LDS double-buffered ----
// C[M,BN] = epi( A1[M,K1]@W1[K1,BN] (+ A2@W2) ), epi: *S+T, relu, resid, gate.
// BN == full output width when C aliases A1 (block reads only its own rows).
// M is padded (MPAD); Mguard bounds the A reads (only matters for proj on x).
template<int BN, bool GATED>
__global__ __launch_bounds__(256, GATED ? 2 : 3)
void gemm_fused(const float* __restrict__ A1, const float* __restrict__ W1, int K1,
                const float* __restrict__ A2, const float* __restrict__ W2, int K2,
                const float* __restrict__ GW, const float* __restrict__ Gb,
                const float* __restrict__ Sc, const float* __restrict__ Tc,
                const float* __restrict__ resid, float* __restrict__ C,
                int Mguard, int do_relu) {
  constexpr int BM = 64;
  constexpr int BK = 16;
  constexpr int TXN = BN / 8;    // threads along n (each covers 8 cols, split 4+4)
  constexpr int TYN = 256 / TXN; // threads along m
  constexpr int TM = BM / TYN;   // rows per thread
  constexpr int WQ = (BK * BN) / 1024;  // float4s per thread for B staging
  __shared__ float As[2][BK][BM + 4];
  __shared__ float Bs[2][BK][BN];
  const int tid = threadIdx.x;
  const int tx = tid % TXN;
  const int ty = tid / TXN;
  const int m0 = blockIdx.x * BM;
  const int lm = tid >> 2;        // 0..63 : A row within tile
  const int lk = (tid & 3) * 4;   // 0,4,8,12

  float acc1[TM][8];
#pragma unroll
  for (int i = 0; i < TM; i++)
#pragma unroll
    for (int j = 0; j < 8; j++) acc1[i][j] = 0.0f;
  float acc2[GATED ? TM : 1][GATED ? 8 : 1];
  if constexpr (GATED) {
#pragma unroll
    for (int i = 0; i < TM; i++)
#pragma unroll
      for (int j = 0; j < 8; j++) acc2[i][j] = 0.0f;
  }

  // B staging map: flat = q*1024 + tid*4 -> coalesced global, bank-spread LDS
  int brow[WQ], bcol[WQ];
#pragma unroll
  for (int q = 0; q < WQ; q++) {
    int f = q * 1024 + tid * 4;
    brow[q] = f / BN;
    bcol[q] = f % BN;
  }

  auto phase = [&](const float* __restrict__ A, const float* __restrict__ W,
                   int K, float (&acc)[TM][8]) {
    const int arow = m0 + lm;
    const bool aok = arow < Mguard;
    const float* Aptr = A + (long)arow * K + lk;
    float4 av = make_float4(0.f, 0.f, 0.f, 0.f);
    float4 wv[WQ];
    // prologue: tile 0 -> regs -> LDS[0]
    if (aok) av = *reinterpret_cast<const float4*>(Aptr);
#pragma unroll
    for (int q = 0; q < WQ; q++)
      wv[q] = *reinterpret_cast<const float4*>(W + (long)brow[q] * BN + bcol[q]);
    As[0][lk + 0][lm] = av.x; As[0][lk + 1][lm] = av.y;
    As[0][lk + 2][lm] = av.z; As[0][lk + 3][lm] = av.w;
#pragma unroll
    for (int q = 0; q < WQ; q++)
      *reinterpret_cast<float4*>(&Bs[0][brow[q]][bcol[q]]) = wv[q];

    const int T = K / BK;
    int buf = 0;
    for (int t = 0; t < T; ++t) {
      __syncthreads();  // publish LDS[buf]; also WAR fence for buf^1 stores below
      if (t + 1 < T) {  // issue next tile's global loads AFTER the barrier
        int kt = (t + 1) * BK;
        if (aok) av = *reinterpret_cast<const float4*>(Aptr + kt);
#pragma unroll
        for (int q = 0; q < WQ; q++)
          wv[q] = *reinterpret_cast<const float4*>(W + (long)(kt + brow[q]) * BN + bcol[q]);
      }
      // compute on LDS[buf] — hides the loads above
#pragma unroll
      for (int k = 0; k < BK; k++) {
        float a[TM];
#pragma unroll
        for (int ii = 0; ii < TM; ii += 4) {
          float4 a4 = *reinterpret_cast<const float4*>(&As[buf][k][ty * TM + ii]);
          a[ii] = a4.x; a[ii + 1] = a4.y; a[ii + 2] = a4.z; a[ii + 3] = a4.w;
        }
        float4 b0 = *reinterpret_cast<const float4*>(&Bs[buf][k][tx * 4]);
        float4 b1 = *reinterpret_cast<const float4*>(&Bs[buf][k][BN / 2 + tx * 4]);
        float b[8] = {b0.x, b0.y, b0.z, b0.w, b1.x, b1.y, b1.z, b1.w};
#pragma unroll
        for (int i = 0; i < TM; i++)
#pragma unroll
          for (int j = 0; j < 8; j++)
            acc[i][j] = fmaf(a[i], b[j], acc[i][j]);
      }
      if (t + 1 < T) {  // store next tile into the other buffer (no barrier needed)
        int nb = buf ^ 1;
        As[nb][lk + 0][lm] = av.x; As[nb][lk + 1][lm] = av.y;
        As[nb][lk + 2][lm] = av.z; As[nb][lk + 3][lm] = av.w;
#pragma unroll
        for (int q = 0; q < WQ; q++)
          *reinterpret_cast<float4*>(&Bs[nb][brow[q]][bcol[q]]) = wv[q];
      }
      buf ^= 1;
    }
  };

  phase(A1, W1, K1, acc1);
  if (A2) phase(A2, W2, K2, acc1);
  if constexpr (GATED) phase(resid, GW, HID, acc2);

  // epilogue
  const int cn0 = tx * 4;
  const int cn1 = BN / 2 + tx * 4;
  float sc[8], tc[8];
#pragma unroll
  for (int j = 0; j < 4; j++) {
    sc[j]     = Sc ? Sc[cn0 + j] : 1.0f;  tc[j]     = Tc[cn0 + j];
    sc[4 + j] = Sc ? Sc[cn1 + j] : 1.0f;  tc[4 + j] = Tc[cn1 + j];
  }
  float gb[8];
  if constexpr (GATED) {
#pragma unroll
    for (int j = 0; j < 4; j++) { gb[j] = Gb[cn0 + j]; gb[4 + j] = Gb[cn1 + j]; }
  }
#pragma unroll
  for (int i = 0; i < TM; i++) {
    int row = m0 + ty * TM + i;
    long base = (long)row * BN;
    float4 p0 = make_float4(0.f, 0.f, 0.f, 0.f), p1 = p0;
    if (resid) {
      p0 = *reinterpret_cast<const float4*>(resid + base + cn0);
      p1 = *reinterpret_cast<const float4*>(resid + base + cn1);
    }
    float out[8];
#pragma unroll
    for (int j = 0; j < 8; j++) {
      float v = acc1[i][j] * sc[j] + tc[j];
      if (do_relu) v = fmaxf(v, 0.0f);
      float p = (j < 4) ? (&p0.x)[j] : (&p1.x)[j - 4];
      if constexpr (GATED) {
        float g = 1.0f / (1.0f + __expf(-(acc2[i][j] + gb[j])));
        v = g * p + (1.0f - g) * (v + p);
      } else if (resid) {
        v += p;
      }
      out[j] = v;
    }
    *reinterpret_cast<float4*>(C + base + cn0) = make_float4(out[0], out[1], out[2], out[3]);
    *reinterpret_cast<float4*>(C + base + cn1) = make_float4(out[4], out[5], out[6], out[7]);
  }
}

// ---------------- classifier stage 2: [M,128] @ [128,40] + b ----------------
__global__ __launch_bounds__(256)
void classifier2(const float* __restrict__ Tin, const float* __restrict__ W,
                 const float* __restrict__ bias, float* __restrict__ out, int M) {
  __shared__ float Ws[DIN * NCLS];
  __shared__ float bs[NCLS];
  __shared__ float Ts[64][DIN + 4];
  int tid = threadIdx.x;
  for (int i = tid; i < DIN * NCLS; i += 256) Ws[i] = W[i];
  if (tid < NCLS) bs[tid] = bias[tid];
  int row0 = blockIdx.x * 64;
  for (int idx = tid; idx < 64 * (DIN / 4); idx += 256) {
    int r = idx / (DIN / 4);
    int c4 = idx % (DIN / 4);
    float4 v = make_float4(0.f, 0.f, 0.f, 0.f);
    if (row0 + r < M) v = *reinterpret_cast<const float4*>(Tin + (long)(row0 + r) * DIN + c4 * 4);
    *reinterpret_cast<float4*>(&Ts[r][c4 * 4]) = v;
  }
  __syncthreads();
  int r = tid >> 2;
  int c0 = (tid & 3) * 10;
  float s[10];
#pragma unroll
  for (int c = 0; c < 10; c++) s[c] = bs[c0 + c];
  for (int k = 0; k < DIN; k++) {
    float a = Ts[r][k];
#pragma unroll
    for (int c = 0; c < 10; c++) s[c] = fmaf(a, Ws[k * NCLS + c0 + c], s[c]);
  }
  if (row0 + r < M) {
#pragma unroll
    for (int c = 0; c < 10; c++) out[(long)(row0 + r) * NCLS + c0 + c] = s[c];
  }
}

extern "C" void kernel_launch(void* const* d_in, const int* in_sizes, int n_in,
                              void* d_out, int out_size, void* d_ws, size_t ws_size,
                              hipStream_t stream) {
  const float* x      = (const float*)d_in[0];
  const int*   ei     = (const int*)d_in[1];
  const float* Wp     = (const float*)d_in[2];
  const float* bp     = (const float*)d_in[3];
  const float* W1l    = (const float*)d_in[4];
  const float* b1l    = (const float*)d_in[5];
  const float* W1r    = (const float*)d_in[6];
  const float* W2l    = (const float*)d_in[7];
  const float* b2l    = (const float*)d_in[8];
  const float* W2r    = (const float*)d_in[9];
  const float* bn1_g  = (const float*)d_in[10];
  const float* bn1_b  = (const float*)d_in[11];
  const float* bn1_m  = (const float*)d_in[12];
  const float* bn1_v  = (const float*)d_in[13];
  const float* bn2_g  = (const float*)d_in[14];
  const float* bn2_b  = (const float*)d_in[15];
  const float* bn2_m  = (const float*)d_in[16];
  const float* bn2_v  = (const float*)d_in[17];
  const float* gate_W = (const float*)d_in[18];
  const float* gate_b = (const float*)d_in[19];
  const float* Wc1    = (const float*)d_in[20];
  const float* bc1    = (const float*)d_in[21];
  const float* Wc2    = (const float*)d_in[22];
  const float* bc2    = (const float*)d_in[23];
  const int* srcp = ei;
  const int* dstp = ei + NEDGES;

  char* wsb = (char*)d_ws;
  size_t off = 0;
  auto alloc = [&](size_t bytes) -> void* {
    void* p = wsb + off;
    off += (bytes + 255) & ~(size_t)255;
    return p;
  };
  float* X0 = (float*)alloc((size_t)MPAD * HID * 4);
  float* X1 = (float*)alloc((size_t)MPAD * HID * 4);
  float* X2 = (float*)alloc((size_t)MPAD * HID * 4);
  int* cnt     = (int*)alloc((size_t)NNODES * 4 * 2);  // cnt + fill, contiguous
  int* fillc   = cnt + NNODES;
  int* row_ptr = (int*)alloc((size_t)(NNODES + 1) * 4);
  float* inv   = (float*)alloc((size_t)NNODES * 4);
  int* col     = (int*)alloc((size_t)NEDGES * 4);
  float* S1 = (float*)alloc(NBLK * HID * 4);
  float* T1 = (float*)alloc(NBLK * HID * 4);
  float* S2 = (float*)alloc(NBLK * HID * 4);
  float* T2 = (float*)alloc(NBLK * HID * 4);

  hipMemsetAsync(cnt, 0, (size_t)NNODES * 4 * 2, stream);
  int eb = (NEDGES + 255) / 256;
  hist_kernel<<<eb, 256, 0, stream>>>(dstp, cnt, NEDGES);
  scan_kernel<<<1, 1024, 0, stream>>>(cnt, row_ptr, inv, NNODES);
  fill_kernel<<<eb, 256, 0, stream>>>(srcp, dstp, row_ptr, fillc, col, NEDGES);
  fold_kernel<<<3, 256, 0, stream>>>(b1l, bn1_g, bn1_b, bn1_m, bn1_v,
                                     b2l, bn2_g, bn2_b, bn2_m, bn2_v, S1, T1, S2, T2);

  int gm = MPAD / 64;  // 782
  // input projection: X0 = x @ Wp + bp (guard A reads at 50000: x is exact-size)
  gemm_fused<256, false><<<gm, 256, 0, stream>>>(
      x, Wp, DIN, nullptr, nullptr, 0, nullptr, nullptr,
      nullptr, bp, nullptr, X0, NNODES, 0);

  float* bufs[3] = {X0, X1, X2};
  int prev = 0;
  for (int i = 0; i < NBLK; ++i) {
    int bm = (prev + 1) % 3;  // mean, then cur (in-place)
    int bh = (prev + 2) % 3;  // h1
    float* P  = bufs[prev];
    float* Mb = bufs[bm];
    float* Hb = bufs[bh];
    // mean of prev
    agg_kernel<<<NNODES, 256, 0, stream>>>(P, Mb, row_ptr, col, inv);
    // h1 = relu(bn1(mean@W1l + prev@W1r + b1l))
    gemm_fused<256, false><<<gm, 256, 0, stream>>>(
        Mb, W1l + (size_t)i * HID * HID, HID,
        P, W1r + (size_t)i * HID * HID, HID,
        nullptr, nullptr, S1 + i * HID, T1 + i * HID, nullptr, Hb, MPAD, 1);
    // mean of h1 (overwrites Mb)
    agg_kernel<<<NNODES, 256, 0, stream>>>(Hb, Mb, row_ptr, col, inv);
    // cur = [gate] relu(bn2(mean2@W2l + h1@W2r + b2l)) + prev   (in-place into Mb)
    if (i == 0) {
      gemm_fused<256, false><<<gm, 256, 0, stream>>>(
          Mb, W2l, HID, Hb, W2r, HID, nullptr, nullptr,
          S2, T2, P, Mb, MPAD, 1);
    } else {
      gemm_fused<256, true><<<gm, 256, 0, stream>>>(
          Mb, W2l + (size_t)i * HID * HID, HID,
          Hb, W2r + (size_t)i * HID * HID, HID,
          gate_W + (size_t)(i - 1) * HID * HID, gate_b + (size_t)(i - 1) * HID,
          S2 + i * HID, T2 + i * HID, P, Mb, MPAD, 1);
    }
    prev = bm;
  }
  // classifier
  float* P  = bufs[prev];
  float* Tb = bufs[(prev + 1) % 3];
  gemm_fused<128, false><<<gm, 256, 0, stream>>>(
      P, Wc1, HID, nullptr, nullptr, 0, nullptr, nullptr,
      nullptr, bc1, nullptr, Tb, MPAD, 1);
  classifier2<<<gm, 256, 0, stream>>>(Tb, Wc2, bc2, (float*)d_out, NNODES);
}

// Round 3
// 3656.602 us; speedup vs baseline: 4.5612x; 4.5612x over previous
//
#include <hip/hip_runtime.h>
#include <hip/hip_bf16.h>
#include <cstdint>

#define NNODES 50000
#define MPAD   50048   // 782 * 64
#define NEDGES 800000
#define DIN 128
#define HID 256
#define NCLS 40
#define NBLK 3
#define EPSV 1e-5f

// async global->LDS, 16B per lane. dst must be wave-uniform; HW adds lane*16.
__device__ __forceinline__ void glds16(const float* gsrc, float* ldst) {
  __builtin_amdgcn_global_load_lds((const __attribute__((address_space(1))) void*)gsrc,
                                   (__attribute__((address_space(3))) void*)ldst,
                                   16, 0, 0);
}

// ---------------- CSR build ----------------
__global__ void hist_kernel(const int* __restrict__ dst, int* __restrict__ cnt, int E) {
  int e = blockIdx.x * blockDim.x + threadIdx.x;
  if (e < E) atomicAdd(&cnt[dst[e]], 1);
}

__global__ void scan_kernel(const int* __restrict__ cnt, int* __restrict__ row_ptr,
                            float* __restrict__ inv_cnt, int N) {
  __shared__ int sums[1024];
  int t = threadIdx.x;
  int chunk = (N + 1023) >> 10;
  int beg = t * chunk;
  int end = beg + chunk; if (end > N) end = N;
  int s = 0;
  for (int i = beg; i < end; ++i) s += cnt[i];
  sums[t] = s;
  __syncthreads();
  for (int off = 1; off < 1024; off <<= 1) {
    int v = 0;
    if (t >= off) v = sums[t - off];
    __syncthreads();
    sums[t] += v;
    __syncthreads();
  }
  int run = (t == 0) ? 0 : sums[t - 1];
  for (int i = beg; i < end; ++i) {
    row_ptr[i] = run;
    int c = cnt[i];
    inv_cnt[i] = 1.0f / (float)(c > 0 ? c : 1);
    run += c;
  }
  if (t == 1023) row_ptr[N] = run;
}

__global__ void fill_kernel(const int* __restrict__ src, const int* __restrict__ dst,
                            const int* __restrict__ row_ptr, int* __restrict__ fillc,
                            int* __restrict__ col, int E) {
  int e = blockIdx.x * blockDim.x + threadIdx.x;
  if (e < E) {
    int d = dst[e];
    int pos = atomicAdd(&fillc[d], 1);
    col[row_ptr[d] + pos] = src[e];
  }
}

// ---------------- mean aggregation: one block per node ----------------
__global__ __launch_bounds__(256)
void agg_kernel(const float* __restrict__ x, float* __restrict__ out,
                const int* __restrict__ row_ptr, const int* __restrict__ col,
                const float* __restrict__ inv_cnt) {
  int n = blockIdx.x;
  int h = threadIdx.x;
  int beg = row_ptr[n], end = row_ptr[n + 1];
  float s = 0.0f;
  for (int j = beg; j < end; ++j) {
    int c = col[j];
    s += x[(long)c * HID + h];
  }
  out[(long)n * HID + h] = s * inv_cnt[n];
}

// ---------------- fold BN params: S = g*rsqrt(v+eps), T = (bl-m)*S + b ----------------
__global__ void fold_kernel(const float* __restrict__ b1l, const float* __restrict__ g1,
                            const float* __restrict__ bb1, const float* __restrict__ m1,
                            const float* __restrict__ v1,
                            const float* __restrict__ b2l, const float* __restrict__ g2,
                            const float* __restrict__ bb2, const float* __restrict__ m2,
                            const float* __restrict__ v2,
                            float* __restrict__ S1, float* __restrict__ T1,
                            float* __restrict__ S2, float* __restrict__ T2) {
  int idx = blockIdx.x * 256 + threadIdx.x;  // 0..767
  float s1 = g1[idx] * rsqrtf(v1[idx] + EPSV);
  S1[idx] = s1;
  T1[idx] = (b1l[idx] - m1[idx]) * s1 + bb1[idx];
  float s2 = g2[idx] * rsqrtf(v2[idx] + EPSV);
  S2[idx] = s2;
  T2[idx] = (b2l[idx] - m2[idx]) * s2 + bb2[idx];
}

// ---------------- fused fp32 GEMM, pipelined, LDS double-buffered, async B ----
// C[M,BN] = epi( A1[M,K1]@W1[K1,BN] (+ A2@W2) ), epi: *S+T, relu, resid, gate.
// BN == full output width when C aliases A1 (block reads only its own rows).
template<int BN, bool GATED>
__global__ __launch_bounds__(256)
void gemm_fused(const float* __restrict__ A1, const float* __restrict__ W1, int K1,
                const float* __restrict__ A2, const float* __restrict__ W2, int K2,
                const float* __restrict__ GW, const float* __restrict__ Gb,
                const float* __restrict__ Sc, const float* __restrict__ Tc,
                const float* __restrict__ resid, float* __restrict__ C,
                int Mguard, int do_relu) {
  constexpr int BM = 64;
  constexpr int BK = 16;
  constexpr int TXN = BN / 8;    // threads along n (each covers 8 cols, split 4+4)
  constexpr int TYN = 256 / TXN; // threads along m
  constexpr int TM = BM / TYN;   // rows per thread
  constexpr int WQ = (BK * BN) / 1024;  // glds16 issues per thread for B tile
  __shared__ float As[2][BK][BM + 4];
  __shared__ float Bs[2][BK * BN];     // flat: glds writes in linear order
  const int tid = threadIdx.x;
  const int tx = tid % TXN;
  const int ty = tid / TXN;
  const int m0 = blockIdx.x * BM;
  const int lm = tid >> 2;        // 0..63 : A row within tile
  const int lk = (tid & 3) * 4;   // 0,4,8,12
  const int wbase = (tid >> 6) * 256;  // wave-uniform LDS offset (floats)

  float acc1[TM][8];
#pragma unroll
  for (int i = 0; i < TM; i++)
#pragma unroll
    for (int j = 0; j < 8; j++) acc1[i][j] = 0.0f;
  float acc2[GATED ? TM : 1][GATED ? 8 : 1];
  if constexpr (GATED) {
#pragma unroll
    for (int i = 0; i < TM; i++)
#pragma unroll
      for (int j = 0; j < 8; j++) acc2[i][j] = 0.0f;
  }

  auto phase = [&](const float* __restrict__ A, const float* __restrict__ W,
                   int K, float (&acc)[TM][8]) {
    const int arow = m0 + lm;
    const bool aok = arow < Mguard;
    const float* Aptr = A + (long)arow * K + lk;
    float4 av = make_float4(0.f, 0.f, 0.f, 0.f);
    // prologue: tile 0. B: async direct to LDS[0]; A: regs -> LDS[0].
#pragma unroll
    for (int q = 0; q < WQ; q++)
      glds16(W + q * 1024 + tid * 4, &Bs[0][q * 1024 + wbase]);
    if (aok) av = *reinterpret_cast<const float4*>(Aptr);
    As[0][lk + 0][lm] = av.x; As[0][lk + 1][lm] = av.y;
    As[0][lk + 2][lm] = av.z; As[0][lk + 3][lm] = av.w;

    const int T = K / BK;
    int buf = 0;
    for (int t = 0; t < T; ++t) {
      __syncthreads();  // drains vmcnt: Bs[buf] (async) + As[buf] published
      if (t + 1 < T) {  // issue next tile's loads right after the barrier
        long koff = (long)(t + 1) * BK * BN;
#pragma unroll
        for (int q = 0; q < WQ; q++)
          glds16(W + koff + q * 1024 + tid * 4, &Bs[buf ^ 1][q * 1024 + wbase]);
        if (aok) av = *reinterpret_cast<const float4*>(Aptr + (t + 1) * BK);
      }
      // compute on LDS[buf] — hides the loads above
#pragma unroll
      for (int k = 0; k < BK; k++) {
        float a[TM];
#pragma unroll
        for (int ii = 0; ii < TM; ii += 4) {
          float4 a4 = *reinterpret_cast<const float4*>(&As[buf][k][ty * TM + ii]);
          a[ii] = a4.x; a[ii + 1] = a4.y; a[ii + 2] = a4.z; a[ii + 3] = a4.w;
        }
        float4 b0 = *reinterpret_cast<const float4*>(&Bs[buf][k * BN + tx * 4]);
        float4 b1 = *reinterpret_cast<const float4*>(&Bs[buf][k * BN + BN / 2 + tx * 4]);
        float b[8] = {b0.x, b0.y, b0.z, b0.w, b1.x, b1.y, b1.z, b1.w};
#pragma unroll
        for (int i = 0; i < TM; i++)
#pragma unroll
          for (int j = 0; j < 8; j++)
            acc[i][j] = fmaf(a[i], b[j], acc[i][j]);
      }
      if (t + 1 < T) {  // A store into the other buffer (WAR-safe: see barrier)
        int nb = buf ^ 1;
        As[nb][lk + 0][lm] = av.x; As[nb][lk + 1][lm] = av.y;
        As[nb][lk + 2][lm] = av.z; As[nb][lk + 3][lm] = av.w;
      }
      buf ^= 1;
    }
  };

  phase(A1, W1, K1, acc1);
  if (A2) phase(A2, W2, K2, acc1);
  if constexpr (GATED) phase(resid, GW, HID, acc2);

  // epilogue
  const int cn0 = tx * 4;
  const int cn1 = BN / 2 + tx * 4;
  float sc[8], tc[8];
#pragma unroll
  for (int j = 0; j < 4; j++) {
    sc[j]     = Sc ? Sc[cn0 + j] : 1.0f;  tc[j]     = Tc[cn0 + j];
    sc[4 + j] = Sc ? Sc[cn1 + j] : 1.0f;  tc[4 + j] = Tc[cn1 + j];
  }
  float gb[8];
  if constexpr (GATED) {
#pragma unroll
    for (int j = 0; j < 4; j++) { gb[j] = Gb[cn0 + j]; gb[4 + j] = Gb[cn1 + j]; }
  }
#pragma unroll
  for (int i = 0; i < TM; i++) {
    int row = m0 + ty * TM + i;
    long base = (long)row * BN;
    float4 p0 = make_float4(0.f, 0.f, 0.f, 0.f), p1 = p0;
    if (resid) {
      p0 = *reinterpret_cast<const float4*>(resid + base + cn0);
      p1 = *reinterpret_cast<const float4*>(resid + base + cn1);
    }
    float out[8];
#pragma unroll
    for (int j = 0; j < 8; j++) {
      float v = acc1[i][j] * sc[j] + tc[j];
      if (do_relu) v = fmaxf(v, 0.0f);
      float p = (j < 4) ? (&p0.x)[j] : (&p1.x)[j - 4];
      if constexpr (GATED) {
        float g = 1.0f / (1.0f + __expf(-(acc2[i][j] + gb[j])));
        v = g * p + (1.0f - g) * (v + p);
      } else if (resid) {
        v += p;
      }
      out[j] = v;
    }
    *reinterpret_cast<float4*>(C + base + cn0) = make_float4(out[0], out[1], out[2], out[3]);
    *reinterpret_cast<float4*>(C + base + cn1) = make_float4(out[4], out[5], out[6], out[7]);
  }
}

// ---------------- classifier stage 2: [M,128] @ [128,40] + b ----------------
__global__ __launch_bounds__(256)
void classifier2(const float* __restrict__ Tin, const float* __restrict__ W,
                 const float* __restrict__ bias, float* __restrict__ out, int M) {
  __shared__ float Ws[DIN * NCLS];
  __shared__ float bs[NCLS];
  __shared__ float Ts[64][DIN + 4];
  int tid = threadIdx.x;
  for (int i = tid; i < DIN * NCLS; i += 256) Ws[i] = W[i];
  if (tid < NCLS) bs[tid] = bias[tid];
  int row0 = blockIdx.x * 64;
  for (int idx = tid; idx < 64 * (DIN / 4); idx += 256) {
    int r = idx / (DIN / 4);
    int c4 = idx % (DIN / 4);
    float4 v = make_float4(0.f, 0.f, 0.f, 0.f);
    if (row0 + r < M) v = *reinterpret_cast<const float4*>(Tin + (long)(row0 + r) * DIN + c4 * 4);
    *reinterpret_cast<float4*>(&Ts[r][c4 * 4]) = v;
  }
  __syncthreads();
  int r = tid >> 2;
  int c0 = (tid & 3) * 10;
  float s[10];
#pragma unroll
  for (int c = 0; c < 10; c++) s[c] = bs[c0 + c];
  for (int k = 0; k < DIN; k++) {
    float a = Ts[r][k];
#pragma unroll
    for (int c = 0; c < 10; c++) s[c] = fmaf(a, Ws[k * NCLS + c0 + c], s[c]);
  }
  if (row0 + r < M) {
#pragma unroll
    for (int c = 0; c < 10; c++) out[(long)(row0 + r) * NCLS + c0 + c] = s[c];
  }
}

extern "C" void kernel_launch(void* const* d_in, const int* in_sizes, int n_in,
                              void* d_out, int out_size, void* d_ws, size_t ws_size,
                              hipStream_t stream) {
  const float* x      = (const float*)d_in[0];
  const int*   ei     = (const int*)d_in[1];
  const float* Wp     = (const float*)d_in[2];
  const float* bp     = (const float*)d_in[3];
  const float* W1l    = (const float*)d_in[4];
  const float* b1l    = (const float*)d_in[5];
  const float* W1r    = (const float*)d_in[6];
  const float* W2l    = (const float*)d_in[7];
  const float* b2l    = (const float*)d_in[8];
  const float* W2r    = (const float*)d_in[9];
  const float* bn1_g  = (const float*)d_in[10];
  const float* bn1_b  = (const float*)d_in[11];
  const float* bn1_m  = (const float*)d_in[12];
  const float* bn1_v  = (const float*)d_in[13];
  const float* bn2_g  = (const float*)d_in[14];
  const float* bn2_b  = (const float*)d_in[15];
  const float* bn2_m  = (const float*)d_in[16];
  const float* bn2_v  = (const float*)d_in[17];
  const float* gate_W = (const float*)d_in[18];
  const float* gate_b = (const float*)d_in[19];
  const float* Wc1    = (const float*)d_in[20];
  const float* bc1    = (const float*)d_in[21];
  const float* Wc2    = (const float*)d_in[22];
  const float* bc2    = (const float*)d_in[23];
  const int* srcp = ei;
  const int* dstp = ei + NEDGES;

  char* wsb = (char*)d_ws;
  size_t off = 0;
  auto alloc = [&](size_t bytes) -> void* {
    void* p = wsb + off;
    off += (bytes + 255) & ~(size_t)255;
    return p;
  };
  float* X0 = (float*)alloc((size_t)MPAD * HID * 4);
  float* X1 = (float*)alloc((size_t)MPAD * HID * 4);
  float* X2 = (float*)alloc((size_t)MPAD * HID * 4);
  int* cnt     = (int*)alloc((size_t)NNODES * 4 * 2);  // cnt + fill, contiguous
  int* fillc   = cnt + NNODES;
  int* row_ptr = (int*)alloc((size_t)(NNODES + 1) * 4);
  float* inv   = (float*)alloc((size_t)NNODES * 4);
  int* col     = (int*)alloc((size_t)NEDGES * 4);
  float* S1 = (float*)alloc(NBLK * HID * 4);
  float* T1 = (float*)alloc(NBLK * HID * 4);
  float* S2 = (float*)alloc(NBLK * HID * 4);
  float* T2 = (float*)alloc(NBLK * HID * 4);

  hipMemsetAsync(cnt, 0, (size_t)NNODES * 4 * 2, stream);
  int eb = (NEDGES + 255) / 256;
  hist_kernel<<<eb, 256, 0, stream>>>(dstp, cnt, NEDGES);
  scan_kernel<<<1, 1024, 0, stream>>>(cnt, row_ptr, inv, NNODES);
  fill_kernel<<<eb, 256, 0, stream>>>(srcp, dstp, row_ptr, fillc, col, NEDGES);
  fold_kernel<<<3, 256, 0, stream>>>(b1l, bn1_g, bn1_b, bn1_m, bn1_v,
                                     b2l, bn2_g, bn2_b, bn2_m, bn2_v, S1, T1, S2, T2);

  int gm = MPAD / 64;  // 782
  // input projection: X0 = x @ Wp + bp (guard A reads at 50000: x is exact-size)
  gemm_fused<256, false><<<gm, 256, 0, stream>>>(
      x, Wp, DIN, nullptr, nullptr, 0, nullptr, nullptr,
      nullptr, bp, nullptr, X0, NNODES, 0);

  float* bufs[3] = {X0, X1, X2};
  int prev = 0;
  for (int i = 0; i < NBLK; ++i) {
    int bm = (prev + 1) % 3;  // mean, then cur (in-place)
    int bh = (prev + 2) % 3;  // h1
    float* P  = bufs[prev];
    float* Mb = bufs[bm];
    float* Hb = bufs[bh];
    // mean of prev
    agg_kernel<<<NNODES, 256, 0, stream>>>(P, Mb, row_ptr, col, inv);
    // h1 = relu(bn1(mean@W1l + prev@W1r + b1l))
    gemm_fused<256, false><<<gm, 256, 0, stream>>>(
        Mb, W1l + (size_t)i * HID * HID, HID,
        P, W1r + (size_t)i * HID * HID, HID,
        nullptr, nullptr, S1 + i * HID, T1 + i * HID, nullptr, Hb, MPAD, 1);
    // mean of h1 (overwrites Mb)
    agg_kernel<<<NNODES, 256, 0, stream>>>(Hb, Mb, row_ptr, col, inv);
    // cur = [gate] relu(bn2(mean2@W2l + h1@W2r + b2l)) + prev   (in-place into Mb)
    if (i == 0) {
      gemm_fused<256, false><<<gm, 256, 0, stream>>>(
          Mb, W2l, HID, Hb, W2r, HID, nullptr, nullptr,
          S2, T2, P, Mb, MPAD, 1);
    } else {
      gemm_fused<256, true><<<gm, 256, 0, stream>>>(
          Mb, W2l + (size_t)i * HID * HID, HID,
          Hb, W2r + (size_t)i * HID * HID, HID,
          gate_W + (size_t)(i - 1) * HID * HID, gate_b + (size_t)(i - 1) * HID,
          S2 + i * HID, T2 + i * HID, P, Mb, MPAD, 1);
    }
    prev = bm;
  }
  // classifier
  float* P  = bufs[prev];
  float* Tb = bufs[(prev + 1) % 3];
  gemm_fused<128, false><<<gm, 256, 0, stream>>>(
      P, Wc1, HID, nullptr, nullptr, 0, nullptr, nullptr,
      nullptr, bc1, nullptr, Tb, MPAD, 1);
  classifier2<<<gm, 256, 0, stream>>>(Tb, Wc2, bc2, (float*)d_out, NNODES);
}

// Round 6
// 2196.592 us; speedup vs baseline: 7.5929x; 1.6647x over previous
//
#include <hip/hip_runtime.h>
#include <hip/hip_bf16.h>
#include <cstdint>

#define NNODES 50000
#define MPAD   50048   // 782 * 64
#define NEDGES 800000
#define DIN 128
#define HID 256
#define NCLS 40
#define NBLK 3
#define EPSV 1e-5f

typedef __bf16 bf16x8 __attribute__((ext_vector_type(8)));
typedef float  f32x4  __attribute__((ext_vector_type(4)));
typedef unsigned short us4v __attribute__((ext_vector_type(4)));
typedef unsigned short us8v __attribute__((ext_vector_type(8)));

// round-to-nearest-even fp32 -> bf16 bits
__device__ __forceinline__ unsigned short bf_rtn(float x) {
  unsigned u = __float_as_uint(x);
  return (unsigned short)((u + 0x7fffu + ((u >> 16) & 1u)) >> 16);
}
__device__ __forceinline__ float bf_f(unsigned short h) {
  return __uint_as_float((unsigned)h << 16);
}
// 3-plane split: x ~= h + m + l (each bf16); residuals exact in fp32
__device__ __forceinline__ void split4(float4 a, us4v& h, us4v& m, us4v& l) {
  float v[4] = {a.x, a.y, a.z, a.w};
#pragma unroll
  for (int i = 0; i < 4; i++) {
    unsigned short hh = bf_rtn(v[i]);
    float r1 = v[i] - bf_f(hh);
    unsigned short mm = bf_rtn(r1);
    float r2 = r1 - bf_f(mm);
    h[i] = hh; m[i] = mm; l[i] = bf_rtn(r2);
  }
}

// async global->LDS, 16B per lane. gsrc is PER-LANE; ldst wave-uniform (HW adds lane*16).
__device__ __forceinline__ void glds16(const void* gsrc, void* ldst) {
  __builtin_amdgcn_global_load_lds((const __attribute__((address_space(1))) void*)gsrc,
                                   (__attribute__((address_space(3))) void*)ldst,
                                   16, 0, 0);
}

// ---------------- CSR build ----------------
__global__ void hist_kernel(const int* __restrict__ dst, int* __restrict__ cnt, int E) {
  int e = blockIdx.x * blockDim.x + threadIdx.x;
  if (e < E) atomicAdd(&cnt[dst[e]], 1);
}

__global__ void scan_kernel(const int* __restrict__ cnt, int* __restrict__ row_ptr,
                            float* __restrict__ inv_cnt, int N) {
  __shared__ int sums[1024];
  int t = threadIdx.x;
  int chunk = (N + 1023) >> 10;
  int beg = t * chunk;
  int end = beg + chunk; if (end > N) end = N;
  int s = 0;
  for (int i = beg; i < end; ++i) s += cnt[i];
  sums[t] = s;
  __syncthreads();
  for (int off = 1; off < 1024; off <<= 1) {
    int v = 0;
    if (t >= off) v = sums[t - off];
    __syncthreads();
    sums[t] += v;
    __syncthreads();
  }
  int run = (t == 0) ? 0 : sums[t - 1];
  for (int i = beg; i < end; ++i) {
    row_ptr[i] = run;
    int c = cnt[i];
    inv_cnt[i] = 1.0f / (float)(c > 0 ? c : 1);
    run += c;
  }
  if (t == 1023) row_ptr[N] = run;
}

__global__ void fill_kernel(const int* __restrict__ src, const int* __restrict__ dst,
                            const int* __restrict__ row_ptr, int* __restrict__ fillc,
                            int* __restrict__ col, int E) {
  int e = blockIdx.x * blockDim.x + threadIdx.x;
  if (e < E) {
    int d = dst[e];
    int pos = atomicAdd(&fillc[d], 1);
    col[row_ptr[d] + pos] = src[e];
  }
}

// ---------------- mean aggregation: one block per node ----------------
__global__ __launch_bounds__(256)
void agg_kernel(const float* __restrict__ x, float* __restrict__ out,
                const int* __restrict__ row_ptr, const int* __restrict__ col,
                const float* __restrict__ inv_cnt) {
  int n = blockIdx.x;
  int h = threadIdx.x;
  int beg = row_ptr[n], end = row_ptr[n + 1];
  float s = 0.0f;
  for (int j = beg; j < end; ++j) {
    int c = col[j];
    s += x[(long)c * HID + h];
  }
  out[(long)n * HID + h] = s * inv_cnt[n];
}

// ---------------- fold BN params ----------------
__global__ void fold_kernel(const float* __restrict__ b1l, const float* __restrict__ g1,
                            const float* __restrict__ bb1, const float* __restrict__ m1,
                            const float* __restrict__ v1,
                            const float* __restrict__ b2l, const float* __restrict__ g2,
                            const float* __restrict__ bb2, const float* __restrict__ m2,
                            const float* __restrict__ v2,
                            float* __restrict__ S1, float* __restrict__ T1,
                            float* __restrict__ S2, float* __restrict__ T2) {
  int idx = blockIdx.x * 256 + threadIdx.x;  // 0..767
  float s1 = g1[idx] * rsqrtf(v1[idx] + EPSV);
  S1[idx] = s1;
  T1[idx] = (b1l[idx] - m1[idx]) * s1 + bb1[idx];
  float s2 = g2[idx] * rsqrtf(v2[idx] + EPSV);
  S2[idx] = s2;
  T2[idx] = (b2l[idx] - m2[idx]) * s2 + bb2[idx];
}

// ---------------- weight prep: fp32 [K][N] -> 3-plane bf16 glds layout ----------
// Per k-tile (32 k): [hm region: n rows x 8 slots x 16B, slot s holds chunk
// d = s^(n&7), d = plane(h=0,m=1)*4 + k8] then [lo region: [k8 0..3][n][16B]].
// Tile stride = N*192 bytes.
#define PREP_TOTAL 368640
struct PrepDescs {
  const float* src[16];
  unsigned dst_off[16];  // bytes
  int N[16];
  int cum[16];           // inclusive prefix end, 16B-chunk count
};
__global__ __launch_bounds__(256)
void prep_kernel(PrepDescs pd, char* out) {
  int i = blockIdx.x * 256 + threadIdx.x;
  if (i >= PREP_TOTAL) return;
  int j = 0;
  while (i >= pd.cum[j]) j++;
  int li = i - (j ? pd.cum[j - 1] : 0);
  int c = li % 12;   // 0..7: hm slot; 8..11: lo chunk
  int t = li / 12;
  int N = pd.N[j];
  int n = t % N;
  int kt = t / N;
  const float* src = pd.src[j];
  char* base = out + pd.dst_off[j] + (size_t)kt * N * 192;
  int p, k8;
  size_t addr;
  if (c < 8) {
    int d = c ^ (n & 7);
    p = d >> 2; k8 = d & 3;
    addr = (size_t)n * 128 + (size_t)c * 16;
  } else {
    p = 2; k8 = c - 8;
    addr = (size_t)N * 128 + ((size_t)k8 * N + n) * 16;
  }
  us8v v;
#pragma unroll
  for (int xj = 0; xj < 8; xj++) {
    float w = src[(size_t)(kt * 32 + k8 * 8 + xj) * N + n];
    unsigned short h = bf_rtn(w);
    if (p == 0) { v[xj] = h; continue; }
    float r1 = w - bf_f(h);
    unsigned short m = bf_rtn(r1);
    v[xj] = (p == 1) ? m : bf_rtn(r1 - bf_f(m));
  }
  *reinterpret_cast<us8v*>(base + addr) = v;
}

// ---------------- fused 3-plane split-bf16 MFMA GEMM ----------------
// C[M,BN] = epi( A1@W1 (+ A2@W2) ), epi: *S+T, relu, resid, gate(acc2 via BG).
// x*y ~= h·h' + h·m' + m·h' + m·m' + h·l' + l·h'  (six MFMAs, ~fp32 precision).
template<int BN, bool GATED>
__global__ __launch_bounds__(256)
void gemm_mfma(const float* __restrict__ A1, const char* __restrict__ B1, int K1,
               const float* __restrict__ A2, const char* __restrict__ B2, int K2,
               const char* __restrict__ BG, const float* __restrict__ Gb,
               const float* __restrict__ Sc, const float* __restrict__ Tc,
               const float* __restrict__ resid, float* __restrict__ C,
               int Mguard, int do_relu) {
  constexpr int NT = BN / 64;          // 16-wide n-tiles per wave
  constexpr int NG = (BN * 48) / 1024; // glds16 issues per thread for B tile
  __shared__ __align__(16) unsigned short A_lds[64][104];  // [m][h0..31|m32..63|l64..95|pad]
  __shared__ __align__(16) char B_lds[BN * 192];
  const int tid  = threadIdx.x;
  const int wv   = tid >> 6;
  const int lane = tid & 63;
  const int l15  = lane & 15;
  const int quad = lane >> 4;
  const int m0   = blockIdx.x * 64;
  const int sm  = tid >> 3;         // 0..31 (r=0), +32 for r=1
  const int skc = (tid & 7) * 4;    // bf16 index within 32

  f32x4 acc1[4][NT];
#pragma unroll
  for (int i = 0; i < 4; i++)
#pragma unroll
    for (int j = 0; j < NT; j++) acc1[i][j] = (f32x4){0.f, 0.f, 0.f, 0.f};
  f32x4 acc2[GATED ? 4 : 1][GATED ? NT : 1];
  if constexpr (GATED) {
#pragma unroll
    for (int i = 0; i < 4; i++)
#pragma unroll
      for (int j = 0; j < NT; j++) acc2[i][j] = (f32x4){0.f, 0.f, 0.f, 0.f};
  }

  auto phase = [&](const float* __restrict__ A, const char* __restrict__ Bp,
                   int K, f32x4 (&acc)[4][NT]) {
    const int KT = K / 32;
    const bool g0 = (m0 + sm) < Mguard;
    const bool g1 = (m0 + 32 + sm) < Mguard;
    const float* ap0 = A + (size_t)(m0 + sm) * K + skc;
    const float* ap1 = A + (size_t)(m0 + 32 + sm) * K + skc;
    for (int kt = 0; kt < KT; ++kt) {
      __syncthreads();  // previous tile fully consumed
      // B tile: async global->LDS (prep layout is exactly the LDS image)
      const char* bsrc = Bp + (size_t)kt * (BN * 192) + wv * (BN * 48) + (size_t)lane * 16;
      char* bdst = B_lds + wv * (BN * 48);
#pragma unroll
      for (int j = 0; j < NG; ++j)
        glds16(bsrc + j * 1024, bdst + j * 1024);
      // A tile: fp32 -> 3-plane split -> LDS
      float4 a0 = make_float4(0.f, 0.f, 0.f, 0.f), a1 = a0;
      if (g0) a0 = *reinterpret_cast<const float4*>(ap0 + kt * 32);
      if (g1) a1 = *reinterpret_cast<const float4*>(ap1 + kt * 32);
      us4v h4, m4, l4;
      split4(a0, h4, m4, l4);
      *reinterpret_cast<us4v*>(&A_lds[sm][skc])      = h4;
      *reinterpret_cast<us4v*>(&A_lds[sm][32 + skc]) = m4;
      *reinterpret_cast<us4v*>(&A_lds[sm][64 + skc]) = l4;
      split4(a1, h4, m4, l4);
      *reinterpret_cast<us4v*>(&A_lds[32 + sm][skc])      = h4;
      *reinterpret_cast<us4v*>(&A_lds[32 + sm][32 + skc]) = m4;
      *reinterpret_cast<us4v*>(&A_lds[32 + sm][64 + skc]) = l4;
      __syncthreads();  // staging visible (drains glds vmcnt too)
      // fragments + MFMA
      bf16x8 ah[4], am[4], al[4];
#pragma unroll
      for (int mt = 0; mt < 4; mt++) {
        const unsigned short* rp = &A_lds[mt * 16 + l15][0];
        ah[mt] = *reinterpret_cast<const bf16x8*>(rp + quad * 8);
        am[mt] = *reinterpret_cast<const bf16x8*>(rp + 32 + quad * 8);
        al[mt] = *reinterpret_cast<const bf16x8*>(rp + 64 + quad * 8);
      }
#pragma unroll
      for (int nt = 0; nt < NT; nt++) {
        int n = wv * (BN / 4) + nt * 16 + l15;
        int sw = n & 7;
        const char* rb = B_lds + (size_t)n * 128;
        bf16x8 bh = *reinterpret_cast<const bf16x8*>(rb + ((quad ^ sw) * 16));
        bf16x8 bm = *reinterpret_cast<const bf16x8*>(rb + (((4 + quad) ^ sw) * 16));
        bf16x8 bl = *reinterpret_cast<const bf16x8*>(
            B_lds + (size_t)BN * 128 + ((size_t)quad * BN + n) * 16);
#pragma unroll
        for (int mt = 0; mt < 4; mt++) {
          acc[mt][nt] = __builtin_amdgcn_mfma_f32_16x16x32_bf16(ah[mt], bh, acc[mt][nt], 0, 0, 0);
          acc[mt][nt] = __builtin_amdgcn_mfma_f32_16x16x32_bf16(ah[mt], bm, acc[mt][nt], 0, 0, 0);
          acc[mt][nt] = __builtin_amdgcn_mfma_f32_16x16x32_bf16(am[mt], bh, acc[mt][nt], 0, 0, 0);
          acc[mt][nt] = __builtin_amdgcn_mfma_f32_16x16x32_bf16(am[mt], bm, acc[mt][nt], 0, 0, 0);
          acc[mt][nt] = __builtin_amdgcn_mfma_f32_16x16x32_bf16(ah[mt], bl, acc[mt][nt], 0, 0, 0);
          acc[mt][nt] = __builtin_amdgcn_mfma_f32_16x16x32_bf16(al[mt], bh, acc[mt][nt], 0, 0, 0);
        }
      }
    }
  };

  phase(A1, B1, K1, acc1);
  if (A2) phase(A2, B2, K2, acc1);
  if constexpr (GATED) phase(resid, BG, HID, acc2);

  // epilogue. C/D layout: col = lane&15, row = quad*4 + reg  [m89-verified]
#pragma unroll
  for (int nt = 0; nt < NT; nt++) {
    int colc = wv * (BN / 4) + nt * 16 + l15;
    float sc = Sc ? Sc[colc] : 1.0f;
    float tc = Tc[colc];
    float gb = 0.0f;
    if constexpr (GATED) gb = Gb[colc];
#pragma unroll
    for (int mt = 0; mt < 4; mt++) {
#pragma unroll
      for (int r = 0; r < 4; r++) {
        int row = m0 + mt * 16 + quad * 4 + r;
        size_t base = (size_t)row * BN + colc;
        float v = acc1[mt][nt][r] * sc + tc;
        if (do_relu) v = fmaxf(v, 0.0f);
        if constexpr (GATED) {
          float p = resid[base];
          float g = 1.0f / (1.0f + __expf(-(acc2[mt][nt][r] + gb)));
          v = g * p + (1.0f - g) * (v + p);
        } else if (resid) {
          v += resid[base];
        }
        C[base] = v;
      }
    }
  }
}

// ---------------- classifier stage 2: [M,128] @ [128,40] + b ----------------
__global__ __launch_bounds__(256)
void classifier2(const float* __restrict__ Tin, const float* __restrict__ W,
                 const float* __restrict__ bias, float* __restrict__ out, int M) {
  __shared__ float Ws[DIN * NCLS];
  __shared__ float bs[NCLS];
  __shared__ float Ts[64][DIN + 4];
  int tid = threadIdx.x;
  for (int i = tid; i < DIN * NCLS; i += 256) Ws[i] = W[i];
  if (tid < NCLS) bs[tid] = bias[tid];
  int row0 = blockIdx.x * 64;
  for (int idx = tid; idx < 64 * (DIN / 4); idx += 256) {
    int r = idx / (DIN / 4);
    int c4 = idx % (DIN / 4);
    float4 v = make_float4(0.f, 0.f, 0.f, 0.f);
    if (row0 + r < M) v = *reinterpret_cast<const float4*>(Tin + (long)(row0 + r) * DIN + c4 * 4);
    *reinterpret_cast<float4*>(&Ts[r][c4 * 4]) = v;
  }
  __syncthreads();
  int r = tid >> 2;
  int c0 = (tid & 3) * 10;
  float s[10];
#pragma unroll
  for (int c = 0; c < 10; c++) s[c] = bs[c0 + c];
  for (int k = 0; k < DIN; k++) {
    float a = Ts[r][k];
#pragma unroll
    for (int c = 0; c < 10; c++) s[c] = fmaf(a, Ws[k * NCLS + c0 + c], s[c]);
  }
  if (row0 + r < M) {
#pragma unroll
    for (int c = 0; c < 10; c++) out[(long)(row0 + r) * NCLS + c0 + c] = s[c];
  }
}

extern "C" void kernel_launch(void* const* d_in, const int* in_sizes, int n_in,
                              void* d_out, int out_size, void* d_ws, size_t ws_size,
                              hipStream_t stream) {
  const float* x      = (const float*)d_in[0];
  const int*   ei     = (const int*)d_in[1];
  const float* Wp     = (const float*)d_in[2];
  const float* bp     = (const float*)d_in[3];
  const float* W1l    = (const float*)d_in[4];
  const float* b1l    = (const float*)d_in[5];
  const float* W1r    = (const float*)d_in[6];
  const float* W2l    = (const float*)d_in[7];
  const float* b2l    = (const float*)d_in[8];
  const float* W2r    = (const float*)d_in[9];
  const float* bn1_g  = (const float*)d_in[10];
  const float* bn1_b  = (const float*)d_in[11];
  const float* bn1_m  = (const float*)d_in[12];
  const float* bn1_v  = (const float*)d_in[13];
  const float* bn2_g  = (const float*)d_in[14];
  const float* bn2_b  = (const float*)d_in[15];
  const float* bn2_m  = (const float*)d_in[16];
  const float* bn2_v  = (const float*)d_in[17];
  const float* gate_W = (const float*)d_in[18];
  const float* gate_b = (const float*)d_in[19];
  const float* Wc1    = (const float*)d_in[20];
  const float* bc1    = (const float*)d_in[21];
  const float* Wc2    = (const float*)d_in[22];
  const float* bc2    = (const float*)d_in[23];
  const int* srcp = ei;
  const int* dstp = ei + NEDGES;

  char* wsb = (char*)d_ws;
  size_t off = 0;
  auto alloc = [&](size_t bytes) -> void* {
    void* p = wsb + off;
    off += (bytes + 255) & ~(size_t)255;
    return p;
  };
  float* X0 = (float*)alloc((size_t)MPAD * HID * 4);
  float* X1 = (float*)alloc((size_t)MPAD * HID * 4);
  float* X2 = (float*)alloc((size_t)MPAD * HID * 4);
  char* prep = (char*)alloc(5898240);  // 5.9 MB: 16 weight matrices, 3-plane bf16
  int* cnt     = (int*)alloc((size_t)NNODES * 4 * 2);
  int* fillc   = cnt + NNODES;
  int* row_ptr = (int*)alloc((size_t)(NNODES + 1) * 4);
  float* inv   = (float*)alloc((size_t)NNODES * 4);
  int* col     = (int*)alloc((size_t)NEDGES * 4);
  float* S1 = (float*)alloc(NBLK * HID * 4);
  float* T1 = (float*)alloc(NBLK * HID * 4);
  float* S2 = (float*)alloc(NBLK * HID * 4);
  float* T2 = (float*)alloc(NBLK * HID * 4);

  // prep region offsets (bytes). Wp: 4 tiles * 256 * 192 = 196608;
  // 256x256 mats: 8 * 256 * 192 = 393216 each; Wc1: 8 * 128 * 192 = 196608.
  auto poff = [](int idx) -> unsigned {
    if (idx == 0) return 0;
    return 196608u + (unsigned)(idx - 1) * 393216u;
  };
  const char* prepWp  = prep + poff(0);
  auto prepW1l = [&](int i) { return prep + poff(1 + i); };
  auto prepW1r = [&](int i) { return prep + poff(4 + i); };
  auto prepW2l = [&](int i) { return prep + poff(7 + i); };
  auto prepW2r = [&](int i) { return prep + poff(10 + i); };
  auto prepGate = [&](int g) { return prep + poff(13 + g); };
  const char* prepWc1 = prep + poff(15);

  PrepDescs pd;
  {
    int c = 0, k = 0;
    auto add = [&](const float* s, int N, int chunks, unsigned doff) {
      pd.src[k] = s; pd.N[k] = N; c += chunks; pd.cum[k] = c; pd.dst_off[k] = doff; k++;
    };
    add(Wp, 256, 12288, poff(0));                                          // KT=4
    for (int i = 0; i < 3; i++) add(W1l + (size_t)i * 65536, 256, 24576, poff(1 + i));
    for (int i = 0; i < 3; i++) add(W1r + (size_t)i * 65536, 256, 24576, poff(4 + i));
    for (int i = 0; i < 3; i++) add(W2l + (size_t)i * 65536, 256, 24576, poff(7 + i));
    for (int i = 0; i < 3; i++) add(W2r + (size_t)i * 65536, 256, 24576, poff(10 + i));
    for (int g = 0; g < 2; g++) add(gate_W + (size_t)g * 65536, 256, 24576, poff(13 + g));
    add(Wc1, 128, 12288, poff(15));                                        // KT=8,N=128
  }

  hipMemsetAsync(cnt, 0, (size_t)NNODES * 4 * 2, stream);
  int eb = (NEDGES + 255) / 256;
  hist_kernel<<<eb, 256, 0, stream>>>(dstp, cnt, NEDGES);
  scan_kernel<<<1, 1024, 0, stream>>>(cnt, row_ptr, inv, NNODES);
  fill_kernel<<<eb, 256, 0, stream>>>(srcp, dstp, row_ptr, fillc, col, NEDGES);
  fold_kernel<<<3, 256, 0, stream>>>(b1l, bn1_g, bn1_b, bn1_m, bn1_v,
                                     b2l, bn2_g, bn2_b, bn2_m, bn2_v, S1, T1, S2, T2);
  prep_kernel<<<PREP_TOTAL / 256, 256, 0, stream>>>(pd, prep);

  int gm = MPAD / 64;  // 782
  // input projection: X0 = x @ Wp + bp
  gemm_mfma<256, false><<<gm, 256, 0, stream>>>(
      x, prepWp, DIN, nullptr, nullptr, 0, nullptr, nullptr,
      nullptr, bp, nullptr, X0, NNODES, 0);

  float* bufs[3] = {X0, X1, X2};
  int prev = 0;
  for (int i = 0; i < NBLK; ++i) {
    int bm = (prev + 1) % 3;
    int bh = (prev + 2) % 3;
    float* P  = bufs[prev];
    float* Mb = bufs[bm];
    float* Hb = bufs[bh];
    agg_kernel<<<NNODES, 256, 0, stream>>>(P, Mb, row_ptr, col, inv);
    gemm_mfma<256, false><<<gm, 256, 0, stream>>>(
        Mb, prepW1l(i), HID, P, prepW1r(i), HID, nullptr, nullptr,
        S1 + i * HID, T1 + i * HID, nullptr, Hb, MPAD, 1);
    agg_kernel<<<NNODES, 256, 0, stream>>>(Hb, Mb, row_ptr, col, inv);
    if (i == 0) {
      gemm_mfma<256, false><<<gm, 256, 0, stream>>>(
          Mb, prepW2l(0), HID, Hb, prepW2r(0), HID, nullptr, nullptr,
          S2, T2, P, Mb, MPAD, 1);
    } else {
      gemm_mfma<256, true><<<gm, 256, 0, stream>>>(
          Mb, prepW2l(i), HID, Hb, prepW2r(i), HID,
          prepGate(i - 1), gate_b + (size_t)(i - 1) * HID,
          S2 + i * HID, T2 + i * HID, P, Mb, MPAD, 1);
    }
    prev = bm;
  }
  float* P  = bufs[prev];
  float* Tb = bufs[(prev + 1) % 3];
  gemm_mfma<128, false><<<gm, 256, 0, stream>>>(
      P, prepWc1, HID, nullptr, nullptr, 0, nullptr, nullptr,
      nullptr, bc1, nullptr, Tb, MPAD, 1);
  classifier2<<<gm, 256, 0, stream>>>(Tb, Wc2, bc2, (float*)d_out, NNODES);
}

// Round 7
// 2124.155 us; speedup vs baseline: 7.8518x; 1.0341x over previous
//
#include <hip/hip_runtime.h>
#include <hip/hip_bf16.h>
#include <cstdint>

#define NNODES 50000
#define MPAD   50048   // 782 * 64
#define NEDGES 800000
#define DIN 128
#define HID 256
#define NCLS 40
#define NBLK 3
#define EPSV 1e-5f

typedef __bf16 bf16x8 __attribute__((ext_vector_type(8)));
typedef float  f32x4  __attribute__((ext_vector_type(4)));
typedef unsigned short us4v __attribute__((ext_vector_type(4)));
typedef unsigned short us8v __attribute__((ext_vector_type(8)));

// round-to-nearest-even fp32 -> bf16 bits
__device__ __forceinline__ unsigned short bf_rtn(float x) {
  unsigned u = __float_as_uint(x);
  return (unsigned short)((u + 0x7fffu + ((u >> 16) & 1u)) >> 16);
}
__device__ __forceinline__ float bf_f(unsigned short h) {
  return __uint_as_float((unsigned)h << 16);
}
// 3-plane split: x ~= h + m + l (each bf16); residuals exact in fp32
__device__ __forceinline__ void split4(float4 a, us4v& h, us4v& m, us4v& l) {
  float v[4] = {a.x, a.y, a.z, a.w};
#pragma unroll
  for (int i = 0; i < 4; i++) {
    unsigned short hh = bf_rtn(v[i]);
    float r1 = v[i] - bf_f(hh);
    unsigned short mm = bf_rtn(r1);
    float r2 = r1 - bf_f(mm);
    h[i] = hh; m[i] = mm; l[i] = bf_rtn(r2);
  }
}

// async global->LDS, 16B per lane. gsrc is PER-LANE; ldst wave-uniform (HW adds lane*16).
__device__ __forceinline__ void glds16(const void* gsrc, void* ldst) {
  __builtin_amdgcn_global_load_lds((const __attribute__((address_space(1))) void*)gsrc,
                                   (__attribute__((address_space(3))) void*)ldst,
                                   16, 0, 0);
}

// ---------------- CSR build ----------------
__global__ void hist_kernel(const int* __restrict__ dst, int* __restrict__ cnt, int E) {
  int e = blockIdx.x * blockDim.x + threadIdx.x;
  if (e < E) atomicAdd(&cnt[dst[e]], 1);
}

__global__ void scan_kernel(const int* __restrict__ cnt, int* __restrict__ row_ptr,
                            float* __restrict__ inv_cnt, int N) {
  __shared__ int sums[1024];
  int t = threadIdx.x;
  int chunk = (N + 1023) >> 10;
  int beg = t * chunk;
  int end = beg + chunk; if (end > N) end = N;
  int s = 0;
  for (int i = beg; i < end; ++i) s += cnt[i];
  sums[t] = s;
  __syncthreads();
  for (int off = 1; off < 1024; off <<= 1) {
    int v = 0;
    if (t >= off) v = sums[t - off];
    __syncthreads();
    sums[t] += v;
    __syncthreads();
  }
  int run = (t == 0) ? 0 : sums[t - 1];
  for (int i = beg; i < end; ++i) {
    row_ptr[i] = run;
    int c = cnt[i];
    inv_cnt[i] = 1.0f / (float)(c > 0 ? c : 1);
    run += c;
  }
  if (t == 1023) row_ptr[N] = run;
}

__global__ void fill_kernel(const int* __restrict__ src, const int* __restrict__ dst,
                            const int* __restrict__ row_ptr, int* __restrict__ fillc,
                            int* __restrict__ col, int E) {
  int e = blockIdx.x * blockDim.x + threadIdx.x;
  if (e < E) {
    int d = dst[e];
    int pos = atomicAdd(&fillc[d], 1);
    col[row_ptr[d] + pos] = src[e];
  }
}

// ---------------- mean aggregation: one block per node ----------------
__global__ __launch_bounds__(256)
void agg_kernel(const float* __restrict__ x, float* __restrict__ out,
                const int* __restrict__ row_ptr, const int* __restrict__ col,
                const float* __restrict__ inv_cnt) {
  int n = blockIdx.x;
  int h = threadIdx.x;
  int beg = row_ptr[n], end = row_ptr[n + 1];
  float s = 0.0f;
  for (int j = beg; j < end; ++j) {
    int c = col[j];
    s += x[(long)c * HID + h];
  }
  out[(long)n * HID + h] = s * inv_cnt[n];
}

// ---------------- fold BN params ----------------
__global__ void fold_kernel(const float* __restrict__ b1l, const float* __restrict__ g1,
                            const float* __restrict__ bb1, const float* __restrict__ m1,
                            const float* __restrict__ v1,
                            const float* __restrict__ b2l, const float* __restrict__ g2,
                            const float* __restrict__ bb2, const float* __restrict__ m2,
                            const float* __restrict__ v2,
                            float* __restrict__ S1, float* __restrict__ T1,
                            float* __restrict__ S2, float* __restrict__ T2) {
  int idx = blockIdx.x * 256 + threadIdx.x;  // 0..767
  float s1 = g1[idx] * rsqrtf(v1[idx] + EPSV);
  S1[idx] = s1;
  T1[idx] = (b1l[idx] - m1[idx]) * s1 + bb1[idx];
  float s2 = g2[idx] * rsqrtf(v2[idx] + EPSV);
  S2[idx] = s2;
  T2[idx] = (b2l[idx] - m2[idx]) * s2 + bb2[idx];
}

// ---------------- weight prep: fp32 [K][N] -> 3-plane bf16 glds layout ----------
// Per k-tile (32 k): [hm region: n rows x 8 slots x 16B, slot s holds chunk
// d = s^(n&7), d = plane(h=0,m=1)*4 + k8] then [lo region: [k8 0..3][n][16B]].
// Tile stride = N*192 bytes.
#define PREP_TOTAL 368640
struct PrepDescs {
  const float* src[16];
  unsigned dst_off[16];  // bytes
  int N[16];
  int cum[16];           // inclusive prefix end, 16B-chunk count
};
__global__ __launch_bounds__(256)
void prep_kernel(PrepDescs pd, char* out) {
  int i = blockIdx.x * 256 + threadIdx.x;
  if (i >= PREP_TOTAL) return;
  int j = 0;
  while (i >= pd.cum[j]) j++;
  int li = i - (j ? pd.cum[j - 1] : 0);
  int c = li % 12;   // 0..7: hm slot; 8..11: lo chunk
  int t = li / 12;
  int N = pd.N[j];
  int n = t % N;
  int kt = t / N;
  const float* src = pd.src[j];
  char* base = out + pd.dst_off[j] + (size_t)kt * N * 192;
  int p, k8;
  size_t addr;
  if (c < 8) {
    int d = c ^ (n & 7);
    p = d >> 2; k8 = d & 3;
    addr = (size_t)n * 128 + (size_t)c * 16;
  } else {
    p = 2; k8 = c - 8;
    addr = (size_t)N * 128 + ((size_t)k8 * N + n) * 16;
  }
  us8v v;
#pragma unroll
  for (int xj = 0; xj < 8; xj++) {
    float w = src[(size_t)(kt * 32 + k8 * 8 + xj) * N + n];
    unsigned short h = bf_rtn(w);
    if (p == 0) { v[xj] = h; continue; }
    float r1 = w - bf_f(h);
    unsigned short m = bf_rtn(r1);
    v[xj] = (p == 1) ? m : bf_rtn(r1 - bf_f(m));
  }
  *reinterpret_cast<us8v*>(base + addr) = v;
}

// ---------------- fused 3-plane split-bf16 MFMA GEMM, prefetch-pipelined ------
// C[M,BN] = epi( A1@W1 (+ A2@W2) ), epi: *S+T, relu, resid, gate(acc2 via BG).
// 512 threads / 8 waves. Double-buffered LDS; glds B(kt+1) issued right after
// the single per-tile barrier, consumed next iteration (latency hidden by MFMA).
// Product order h·h,h·m,m·h,m·m,h·l,l·h is FIXED (absmax determinism).
template<int BM, int BN, bool GATED>
__global__ __launch_bounds__(512)
void gemm_mfma(const float* __restrict__ A1, const char* __restrict__ B1, int K1,
               const float* __restrict__ A2, const char* __restrict__ B2, int K2,
               const char* __restrict__ BG, const float* __restrict__ Gb,
               const float* __restrict__ Sc, const float* __restrict__ Tc,
               const float* __restrict__ resid, float* __restrict__ C,
               int Mguard, int do_relu) {
  constexpr int WN = BN / 64;            // waves along n (4 or 2)
  constexpr int WM = 8 / WN;             // waves along m
  constexpr int RB = BM / WM;            // rows per wave
  constexpr int MT = RB / 16;            // 16-row m-tiles per wave
  constexpr int APITCH = 104;            // shorts per A row (96 data + 8 pad, 16B-mult)
  constexpr int AL = (BM * 32) / 2048;   // float4 A-loads per thread
  constexpr int NG = (BN * 24) / 1024;   // glds16 per thread (per-wave region BN*24 B)
  __shared__ __align__(16) unsigned short A_lds[2][BM][APITCH];
  __shared__ __align__(16) char B_lds[2][BN * 192];
  const int tid  = threadIdx.x;
  const int wv   = tid >> 6;
  const int lane = tid & 63;
  const int l15  = lane & 15;
  const int quad = lane >> 4;
  const int wm   = wv / WN;
  const int wn   = wv % WN;
  const int m0   = blockIdx.x * BM;
  const int sr   = tid >> 3;        // A staging row (0..63)
  const int skc  = (tid & 7) * 4;   // A staging col (fp32 within 32)

  f32x4 acc1[MT][4];
#pragma unroll
  for (int i = 0; i < MT; i++)
#pragma unroll
    for (int j = 0; j < 4; j++) acc1[i][j] = (f32x4){0.f, 0.f, 0.f, 0.f};
  f32x4 acc2[GATED ? MT : 1][GATED ? 4 : 1];
  if constexpr (GATED) {
#pragma unroll
    for (int i = 0; i < MT; i++)
#pragma unroll
      for (int j = 0; j < 4; j++) acc2[i][j] = (f32x4){0.f, 0.f, 0.f, 0.f};
  }

  int buf = 0;

  auto issueB = [&](const char* Bp, int kt, int b) {
    const char* bsrc = Bp + (size_t)kt * (BN * 192) + wv * (BN * 24) + (size_t)lane * 16;
    char* bdst = &B_lds[b][wv * (BN * 24)];
#pragma unroll
    for (int j = 0; j < NG; ++j)
      glds16(bsrc + j * 1024, bdst + j * 1024);
  };
  auto storeA = [&](float4 (&a)[AL], int b) {
#pragma unroll
    for (int i = 0; i < AL; i++) {
      us4v h4, m4, l4;
      split4(a[i], h4, m4, l4);
      unsigned short* rp = &A_lds[b][sr + i * 64][0];
      *reinterpret_cast<us4v*>(rp + skc)      = h4;
      *reinterpret_cast<us4v*>(rp + 32 + skc) = m4;
      *reinterpret_cast<us4v*>(rp + 64 + skc) = l4;
    }
  };

  auto phase = [&](const float* __restrict__ A, const char* __restrict__ Bp,
                   int K, f32x4 (&acc)[MT][4]) {
    const int KT = K / 32;
    bool g[AL];
    const float* ap[AL];
#pragma unroll
    for (int i = 0; i < AL; i++) {
      int row = m0 + sr + i * 64;
      g[i] = row < Mguard;
      ap[i] = A + (size_t)row * K + skc;
    }
    // prologue: tile 0 -> current buf (WAR-safe: see barrier analysis)
    issueB(Bp, 0, buf);
    {
      float4 a[AL];
#pragma unroll
      for (int i = 0; i < AL; i++)
        a[i] = g[i] ? *reinterpret_cast<const float4*>(ap[i]) : make_float4(0.f, 0.f, 0.f, 0.f);
      storeA(a, buf);
    }
    for (int kt = 0; kt < KT; ++kt) {
      __syncthreads();  // drains glds B(kt) + publishes A_lds[buf]
      const bool pf = (kt + 1 < KT);
      float4 a[AL];
      if (pf) {
        issueB(Bp, kt + 1, buf ^ 1);  // in flight across the compute below
#pragma unroll
        for (int i = 0; i < AL; i++)
          a[i] = g[i] ? *reinterpret_cast<const float4*>(ap[i] + (kt + 1) * 32)
                      : make_float4(0.f, 0.f, 0.f, 0.f);
      }
      // compute tile kt from LDS[buf]
      bf16x8 ah[MT], am[MT], al[MT];
#pragma unroll
      for (int mt = 0; mt < MT; mt++) {
        const unsigned short* rp = &A_lds[buf][wm * RB + mt * 16 + l15][0];
        ah[mt] = *reinterpret_cast<const bf16x8*>(rp + quad * 8);
        am[mt] = *reinterpret_cast<const bf16x8*>(rp + 32 + quad * 8);
        al[mt] = *reinterpret_cast<const bf16x8*>(rp + 64 + quad * 8);
      }
#pragma unroll
      for (int nt = 0; nt < 4; nt++) {
        int n = wn * 64 + nt * 16 + l15;
        int sw = n & 7;
        const char* rb = &B_lds[buf][(size_t)n * 128];
        bf16x8 bh = *reinterpret_cast<const bf16x8*>(rb + ((quad ^ sw) * 16));
        bf16x8 bm = *reinterpret_cast<const bf16x8*>(rb + (((4 + quad) ^ sw) * 16));
        bf16x8 bl = *reinterpret_cast<const bf16x8*>(
            &B_lds[buf][(size_t)BN * 128 + ((size_t)quad * BN + n) * 16]);
#pragma unroll
        for (int mt = 0; mt < MT; mt++) {
          acc[mt][nt] = __builtin_amdgcn_mfma_f32_16x16x32_bf16(ah[mt], bh, acc[mt][nt], 0, 0, 0);
          acc[mt][nt] = __builtin_amdgcn_mfma_f32_16x16x32_bf16(ah[mt], bm, acc[mt][nt], 0, 0, 0);
          acc[mt][nt] = __builtin_amdgcn_mfma_f32_16x16x32_bf16(am[mt], bh, acc[mt][nt], 0, 0, 0);
          acc[mt][nt] = __builtin_amdgcn_mfma_f32_16x16x32_bf16(am[mt], bm, acc[mt][nt], 0, 0, 0);
          acc[mt][nt] = __builtin_amdgcn_mfma_f32_16x16x32_bf16(ah[mt], bl, acc[mt][nt], 0, 0, 0);
          acc[mt][nt] = __builtin_amdgcn_mfma_f32_16x16x32_bf16(al[mt], bh, acc[mt][nt], 0, 0, 0);
        }
      }
      if (pf) storeA(a, buf ^ 1);
      buf ^= 1;
    }
  };

  phase(A1, B1, K1, acc1);
  if (A2) phase(A2, B2, K2, acc1);
  if constexpr (GATED) phase(resid, BG, HID, acc2);

  // epilogue. C/D layout: col = lane&15, row = quad*4 + reg  [m89-verified]
#pragma unroll
  for (int nt = 0; nt < 4; nt++) {
    int colc = wn * 64 + nt * 16 + l15;
    float sc = Sc ? Sc[colc] : 1.0f;
    float tc = Tc[colc];
    float gb = 0.0f;
    if constexpr (GATED) gb = Gb[colc];
#pragma unroll
    for (int mt = 0; mt < MT; mt++) {
#pragma unroll
      for (int r = 0; r < 4; r++) {
        int row = m0 + wm * RB + mt * 16 + quad * 4 + r;
        size_t base = (size_t)row * BN + colc;
        float v = acc1[mt][nt][r] * sc + tc;
        if (do_relu) v = fmaxf(v, 0.0f);
        if constexpr (GATED) {
          float p = resid[base];
          float g = 1.0f / (1.0f + __expf(-(acc2[mt][nt][r] + gb)));
          v = g * p + (1.0f - g) * (v + p);
        } else if (resid) {
          v += resid[base];
        }
        C[base] = v;
      }
    }
  }
}

// ---------------- classifier stage 2: [M,128] @ [128,40] + b ----------------
__global__ __launch_bounds__(256)
void classifier2(const float* __restrict__ Tin, const float* __restrict__ W,
                 const float* __restrict__ bias, float* __restrict__ out, int M) {
  __shared__ float Ws[DIN * NCLS];
  __shared__ float bs[NCLS];
  __shared__ float Ts[64][DIN + 4];
  int tid = threadIdx.x;
  for (int i = tid; i < DIN * NCLS; i += 256) Ws[i] = W[i];
  if (tid < NCLS) bs[tid] = bias[tid];
  int row0 = blockIdx.x * 64;
  for (int idx = tid; idx < 64 * (DIN / 4); idx += 256) {
    int r = idx / (DIN / 4);
    int c4 = idx % (DIN / 4);
    float4 v = make_float4(0.f, 0.f, 0.f, 0.f);
    if (row0 + r < M) v = *reinterpret_cast<const float4*>(Tin + (long)(row0 + r) * DIN + c4 * 4);
    *reinterpret_cast<float4*>(&Ts[r][c4 * 4]) = v;
  }
  __syncthreads();
  int r = tid >> 2;
  int c0 = (tid & 3) * 10;
  float s[10];
#pragma unroll
  for (int c = 0; c < 10; c++) s[c] = bs[c0 + c];
  for (int k = 0; k < DIN; k++) {
    float a = Ts[r][k];
#pragma unroll
    for (int c = 0; c < 10; c++) s[c] = fmaf(a, Ws[k * NCLS + c0 + c], s[c]);
  }
  if (row0 + r < M) {
#pragma unroll
    for (int c = 0; c < 10; c++) out[(long)(row0 + r) * NCLS + c0 + c] = s[c];
  }
}

extern "C" void kernel_launch(void* const* d_in, const int* in_sizes, int n_in,
                              void* d_out, int out_size, void* d_ws, size_t ws_size,
                              hipStream_t stream) {
  const float* x      = (const float*)d_in[0];
  const int*   ei     = (const int*)d_in[1];
  const float* Wp     = (const float*)d_in[2];
  const float* bp     = (const float*)d_in[3];
  const float* W1l    = (const float*)d_in[4];
  const float* b1l    = (const float*)d_in[5];
  const float* W1r    = (const float*)d_in[6];
  const float* W2l    = (const float*)d_in[7];
  const float* b2l    = (const float*)d_in[8];
  const float* W2r    = (const float*)d_in[9];
  const float* bn1_g  = (const float*)d_in[10];
  const float* bn1_b  = (const float*)d_in[11];
  const float* bn1_m  = (const float*)d_in[12];
  const float* bn1_v  = (const float*)d_in[13];
  const float* bn2_g  = (const float*)d_in[14];
  const float* bn2_b  = (const float*)d_in[15];
  const float* bn2_m  = (const float*)d_in[16];
  const float* bn2_v  = (const float*)d_in[17];
  const float* gate_W = (const float*)d_in[18];
  const float* gate_b = (const float*)d_in[19];
  const float* Wc1    = (const float*)d_in[20];
  const float* bc1    = (const float*)d_in[21];
  const float* Wc2    = (const float*)d_in[22];
  const float* bc2    = (const float*)d_in[23];
  const int* srcp = ei;
  const int* dstp = ei + NEDGES;

  char* wsb = (char*)d_ws;
  size_t off = 0;
  auto alloc = [&](size_t bytes) -> void* {
    void* p = wsb + off;
    off += (bytes + 255) & ~(size_t)255;
    return p;
  };
  float* X0 = (float*)alloc((size_t)MPAD * HID * 4);
  float* X1 = (float*)alloc((size_t)MPAD * HID * 4);
  float* X2 = (float*)alloc((size_t)MPAD * HID * 4);
  char* prep = (char*)alloc(5898240);  // 5.9 MB: 16 weight matrices, 3-plane bf16
  int* cnt     = (int*)alloc((size_t)NNODES * 4 * 2);
  int* fillc   = cnt + NNODES;
  int* row_ptr = (int*)alloc((size_t)(NNODES + 1) * 4);
  float* inv   = (float*)alloc((size_t)NNODES * 4);
  int* col     = (int*)alloc((size_t)NEDGES * 4);
  float* S1 = (float*)alloc(NBLK * HID * 4);
  float* T1 = (float*)alloc(NBLK * HID * 4);
  float* S2 = (float*)alloc(NBLK * HID * 4);
  float* T2 = (float*)alloc(NBLK * HID * 4);

  // prep region offsets (bytes). Wp: 4 tiles * 256 * 192 = 196608;
  // 256x256 mats: 8 * 256 * 192 = 393216 each; Wc1: 8 * 128 * 192 = 196608.
  auto poff = [](int idx) -> unsigned {
    if (idx == 0) return 0;
    return 196608u + (unsigned)(idx - 1) * 393216u;
  };
  const char* prepWp  = prep + poff(0);
  auto prepW1l = [&](int i) { return prep + poff(1 + i); };
  auto prepW1r = [&](int i) { return prep + poff(4 + i); };
  auto prepW2l = [&](int i) { return prep + poff(7 + i); };
  auto prepW2r = [&](int i) { return prep + poff(10 + i); };
  auto prepGate = [&](int g) { return prep + poff(13 + g); };
  const char* prepWc1 = prep + poff(15);

  PrepDescs pd;
  {
    int c = 0, k = 0;
    auto add = [&](const float* s, int N, int chunks, unsigned doff) {
      pd.src[k] = s; pd.N[k] = N; c += chunks; pd.cum[k] = c; pd.dst_off[k] = doff; k++;
    };
    add(Wp, 256, 12288, poff(0));                                          // KT=4
    for (int i = 0; i < 3; i++) add(W1l + (size_t)i * 65536, 256, 24576, poff(1 + i));
    for (int i = 0; i < 3; i++) add(W1r + (size_t)i * 65536, 256, 24576, poff(4 + i));
    for (int i = 0; i < 3; i++) add(W2l + (size_t)i * 65536, 256, 24576, poff(7 + i));
    for (int i = 0; i < 3; i++) add(W2r + (size_t)i * 65536, 256, 24576, poff(10 + i));
    for (int g = 0; g < 2; g++) add(gate_W + (size_t)g * 65536, 256, 24576, poff(13 + g));
    add(Wc1, 128, 12288, poff(15));                                        // KT=8,N=128
  }

  hipMemsetAsync(cnt, 0, (size_t)NNODES * 4 * 2, stream);
  int eb = (NEDGES + 255) / 256;
  hist_kernel<<<eb, 256, 0, stream>>>(dstp, cnt, NEDGES);
  scan_kernel<<<1, 1024, 0, stream>>>(cnt, row_ptr, inv, NNODES);
  fill_kernel<<<eb, 256, 0, stream>>>(srcp, dstp, row_ptr, fillc, col, NEDGES);
  fold_kernel<<<3, 256, 0, stream>>>(b1l, bn1_g, bn1_b, bn1_m, bn1_v,
                                     b2l, bn2_g, bn2_b, bn2_m, bn2_v, S1, T1, S2, T2);
  prep_kernel<<<PREP_TOTAL / 256, 256, 0, stream>>>(pd, prep);

  int gm128 = MPAD / 128;  // 391
  int gm64  = MPAD / 64;   // 782
  // input projection: X0 = x @ Wp + bp
  gemm_mfma<128, 256, false><<<gm128, 512, 0, stream>>>(
      x, prepWp, DIN, nullptr, nullptr, 0, nullptr, nullptr,
      nullptr, bp, nullptr, X0, NNODES, 0);

  float* bufs[3] = {X0, X1, X2};
  int prev = 0;
  for (int i = 0; i < NBLK; ++i) {
    int bm = (prev + 1) % 3;
    int bh = (prev + 2) % 3;
    float* P  = bufs[prev];
    float* Mb = bufs[bm];
    float* Hb = bufs[bh];
    agg_kernel<<<NNODES, 256, 0, stream>>>(P, Mb, row_ptr, col, inv);
    gemm_mfma<128, 256, false><<<gm128, 512, 0, stream>>>(
        Mb, prepW1l(i), HID, P, prepW1r(i), HID, nullptr, nullptr,
        S1 + i * HID, T1 + i * HID, nullptr, Hb, MPAD, 1);
    agg_kernel<<<NNODES, 256, 0, stream>>>(Hb, Mb, row_ptr, col, inv);
    if (i == 0) {
      gemm_mfma<128, 256, false><<<gm128, 512, 0, stream>>>(
          Mb, prepW2l(0), HID, Hb, prepW2r(0), HID, nullptr, nullptr,
          S2, T2, P, Mb, MPAD, 1);
    } else {
      gemm_mfma<64, 256, true><<<gm64, 512, 0, stream>>>(
          Mb, prepW2l(i), HID, Hb, prepW2r(i), HID,
          prepGate(i - 1), gate_b + (size_t)(i - 1) * HID,
          S2 + i * HID, T2 + i * HID, P, Mb, MPAD, 1);
    }
    prev = bm;
  }
  float* P  = bufs[prev];
  float* Tb = bufs[(prev + 1) % 3];
  gemm_mfma<128, 128, false><<<gm128, 512, 0, stream>>>(
      P, prepWc1, HID, nullptr, nullptr, 0, nullptr, nullptr,
      nullptr, bc1, nullptr, Tb, MPAD, 1);
  classifier2<<<gm128 * 2, 256, 0, stream>>>(Tb, Wc2, bc2, (float*)d_out, NNODES);
}

// Round 8
// 2106.807 us; speedup vs baseline: 7.9165x; 1.0082x over previous
//
#include <hip/hip_runtime.h>
#include <hip/hip_bf16.h>
#include <cstdint>

#define NNODES 50000
#define MPAD   50048   // 782 * 64
#define NEDGES 800000
#define DIN 128
#define HID 256
#define NCLS 40
#define NBLK 3
#define EPSV 1e-5f

typedef __bf16 bf16x8 __attribute__((ext_vector_type(8)));
typedef float  f32x4  __attribute__((ext_vector_type(4)));
typedef unsigned short us4v __attribute__((ext_vector_type(4)));
typedef unsigned short us8v __attribute__((ext_vector_type(8)));

// round-to-nearest-even fp32 -> bf16 bits
__device__ __forceinline__ unsigned short bf_rtn(float x) {
  unsigned u = __float_as_uint(x);
  return (unsigned short)((u + 0x7fffu + ((u >> 16) & 1u)) >> 16);
}
__device__ __forceinline__ float bf_f(unsigned short h) {
  return __uint_as_float((unsigned)h << 16);
}
// 3-plane split: x ~= h + m + l (each bf16); residuals exact in fp32
__device__ __forceinline__ void split4(float4 a, us4v& h, us4v& m, us4v& l) {
  float v[4] = {a.x, a.y, a.z, a.w};
#pragma unroll
  for (int i = 0; i < 4; i++) {
    unsigned short hh = bf_rtn(v[i]);
    float r1 = v[i] - bf_f(hh);
    unsigned short mm = bf_rtn(r1);
    float r2 = r1 - bf_f(mm);
    h[i] = hh; m[i] = mm; l[i] = bf_rtn(r2);
  }
}

// async global->LDS, 16B per lane. gsrc is PER-LANE; ldst wave-uniform (HW adds lane*16).
__device__ __forceinline__ void glds16(const void* gsrc, void* ldst) {
  __builtin_amdgcn_global_load_lds((const __attribute__((address_space(1))) void*)gsrc,
                                   (__attribute__((address_space(3))) void*)ldst,
                                   16, 0, 0);
}

// ---------------- CSR build ----------------
__global__ void hist_kernel(const int* __restrict__ dst, int* __restrict__ cnt, int E) {
  int e = blockIdx.x * blockDim.x + threadIdx.x;
  if (e < E) atomicAdd(&cnt[dst[e]], 1);
}

__global__ void scan_kernel(const int* __restrict__ cnt, int* __restrict__ row_ptr,
                            float* __restrict__ inv_cnt, int N) {
  __shared__ int sums[1024];
  int t = threadIdx.x;
  int chunk = (N + 1023) >> 10;
  int beg = t * chunk;
  int end = beg + chunk; if (end > N) end = N;
  int s = 0;
  for (int i = beg; i < end; ++i) s += cnt[i];
  sums[t] = s;
  __syncthreads();
  for (int off = 1; off < 1024; off <<= 1) {
    int v = 0;
    if (t >= off) v = sums[t - off];
    __syncthreads();
    sums[t] += v;
    __syncthreads();
  }
  int run = (t == 0) ? 0 : sums[t - 1];
  for (int i = beg; i < end; ++i) {
    row_ptr[i] = run;
    int c = cnt[i];
    inv_cnt[i] = 1.0f / (float)(c > 0 ? c : 1);
    run += c;
  }
  if (t == 1023) row_ptr[N] = run;
}

__global__ void fill_kernel(const int* __restrict__ src, const int* __restrict__ dst,
                            const int* __restrict__ row_ptr, int* __restrict__ fillc,
                            int* __restrict__ col, int E) {
  int e = blockIdx.x * blockDim.x + threadIdx.x;
  if (e < E) {
    int d = dst[e];
    int pos = atomicAdd(&fillc[d], 1);
    col[row_ptr[d] + pos] = src[e];
  }
}

// ---------------- mean aggregation: one block per node ----------------
__global__ __launch_bounds__(256)
void agg_kernel(const float* __restrict__ x, float* __restrict__ out,
                const int* __restrict__ row_ptr, const int* __restrict__ col,
                const float* __restrict__ inv_cnt) {
  int n = blockIdx.x;
  int h = threadIdx.x;
  int beg = row_ptr[n], end = row_ptr[n + 1];
  float s = 0.0f;
  for (int j = beg; j < end; ++j) {
    int c = col[j];
    s += x[(long)c * HID + h];
  }
  out[(long)n * HID + h] = s * inv_cnt[n];
}

// ---------------- fold BN params ----------------
__global__ void fold_kernel(const float* __restrict__ b1l, const float* __restrict__ g1,
                            const float* __restrict__ bb1, const float* __restrict__ m1,
                            const float* __restrict__ v1,
                            const float* __restrict__ b2l, const float* __restrict__ g2,
                            const float* __restrict__ bb2, const float* __restrict__ m2,
                            const float* __restrict__ v2,
                            float* __restrict__ S1, float* __restrict__ T1,
                            float* __restrict__ S2, float* __restrict__ T2) {
  int idx = blockIdx.x * 256 + threadIdx.x;  // 0..767
  float s1 = g1[idx] * rsqrtf(v1[idx] + EPSV);
  S1[idx] = s1;
  T1[idx] = (b1l[idx] - m1[idx]) * s1 + bb1[idx];
  float s2 = g2[idx] * rsqrtf(v2[idx] + EPSV);
  S2[idx] = s2;
  T2[idx] = (b2l[idx] - m2[idx]) * s2 + bb2[idx];
}

// ---------------- weight prep: fp32 [K][N] -> 3-plane bf16 glds layout ----------
// Per k-tile (32 k): [hm region: n rows x 8 slots x 16B, slot s holds chunk
// d = s^(n&7), d = plane(h=0,m=1)*4 + k8] then [lo region: [k8 0..3][n][16B]].
// Tile stride = N*192 bytes.
#define PREP_TOTAL 368640
struct PrepDescs {
  const float* src[16];
  unsigned dst_off[16];  // bytes
  int N[16];
  int cum[16];           // inclusive prefix end, 16B-chunk count
};
__global__ __launch_bounds__(256)
void prep_kernel(PrepDescs pd, char* out) {
  int i = blockIdx.x * 256 + threadIdx.x;
  if (i >= PREP_TOTAL) return;
  int j = 0;
  while (i >= pd.cum[j]) j++;
  int li = i - (j ? pd.cum[j - 1] : 0);
  int c = li % 12;   // 0..7: hm slot; 8..11: lo chunk
  int t = li / 12;
  int N = pd.N[j];
  int n = t % N;
  int kt = t / N;
  const float* src = pd.src[j];
  char* base = out + pd.dst_off[j] + (size_t)kt * N * 192;
  int p, k8;
  size_t addr;
  if (c < 8) {
    int d = c ^ (n & 7);
    p = d >> 2; k8 = d & 3;
    addr = (size_t)n * 128 + (size_t)c * 16;
  } else {
    p = 2; k8 = c - 8;
    addr = (size_t)N * 128 + ((size_t)k8 * N + n) * 16;
  }
  us8v v;
#pragma unroll
  for (int xj = 0; xj < 8; xj++) {
    float w = src[(size_t)(kt * 32 + k8 * 8 + xj) * N + n];
    unsigned short h = bf_rtn(w);
    if (p == 0) { v[xj] = h; continue; }
    float r1 = w - bf_f(h);
    unsigned short m = bf_rtn(r1);
    v[xj] = (p == 1) ? m : bf_rtn(r1 - bf_f(m));
  }
  *reinterpret_cast<us8v*>(base + addr) = v;
}

// ---------------- fused 3-plane split-bf16 MFMA GEMM ----------------
// Tile 64x128, 256 threads (4 waves: 2x2), double-buffered, prefetch-pipelined.
// Grid: (MPAD/64) * (Bn/128); n-block fastest (same-A blocks adjacent for L2).
// ds_reads issued BEFORE next tile's glds so no vmcnt wait can precede them.
// Product order h·h,h·m,m·h,m·m,h·l,l·h and k-order FIXED (absmax determinism).
template<bool GATED>
__global__ __launch_bounds__(256)
void gemm_mfma(const float* __restrict__ A1, const char* __restrict__ B1, int K1,
               const float* __restrict__ A2, const char* __restrict__ B2, int K2,
               const char* __restrict__ BG, const float* __restrict__ Gb,
               const float* __restrict__ Sc, const float* __restrict__ Tc,
               const float* __restrict__ resid, float* __restrict__ C,
               int Bn, int Mguard, int do_relu) {
  __shared__ __align__(16) unsigned short A_lds[2][64][104];  // 26,624 B
  __shared__ __align__(16) char B_lds[2][24576];              // 49,152 B
  const int tid  = threadIdx.x;
  const int wv   = tid >> 6;
  const int lane = tid & 63;
  const int l15  = lane & 15;
  const int quad = lane >> 4;
  const int NC   = Bn >> 7;                    // column-blocks (1 or 2)
  const int n0   = (blockIdx.x % NC) * 128;    // global col offset
  const int m0   = (blockIdx.x / NC) * 64;
  const int wm   = wv >> 1;                    // 0..1 (32-row slice)
  const int wn   = wv & 1;                     // 0..1 (64-col slice)
  const int sr   = tid >> 3;                   // A staging row 0..31 (+32)
  const int skc  = (tid & 7) * 4;              // A staging col (fp32 in 32)

  f32x4 acc1[2][4];
#pragma unroll
  for (int i = 0; i < 2; i++)
#pragma unroll
    for (int j = 0; j < 4; j++) acc1[i][j] = (f32x4){0.f, 0.f, 0.f, 0.f};
  f32x4 acc2[GATED ? 2 : 1][GATED ? 4 : 1];
  if constexpr (GATED) {
#pragma unroll
    for (int i = 0; i < 2; i++)
#pragma unroll
      for (int j = 0; j < 4; j++) acc2[i][j] = (f32x4){0.f, 0.f, 0.f, 0.f};
  }

  int buf = 0;

  // B image per block-tile: [hm: 128 rows x 128B][lo: 4 k8 x 128 rows x 16B]
  auto issueB = [&](const char* Bp, int kt, int b) {
    const char* tb = Bp + (size_t)kt * ((size_t)Bn * 192);
#pragma unroll
    for (int j = 0; j < 6; ++j) {
      int o = wv * 6144 + j * 1024;
      const char* src;
      if (o < 16384) {
        src = tb + (size_t)n0 * 128 + o;
      } else {
        int ol = o - 16384;
        int k8 = ol >> 11;
        int within = ol & 2047;
        src = tb + (size_t)Bn * 128 + (size_t)k8 * Bn * 16 + (size_t)n0 * 16 + within;
      }
      glds16(src + (size_t)lane * 16, &B_lds[b][o]);
    }
  };
  auto storeA = [&](float4 (&a)[2], int b) {
#pragma unroll
    for (int i = 0; i < 2; i++) {
      us4v h4, m4, l4;
      split4(a[i], h4, m4, l4);
      unsigned short* rp = &A_lds[b][sr + i * 32][0];
      *reinterpret_cast<us4v*>(rp + skc)      = h4;
      *reinterpret_cast<us4v*>(rp + 32 + skc) = m4;
      *reinterpret_cast<us4v*>(rp + 64 + skc) = l4;
    }
  };

  auto phase = [&](const float* __restrict__ A, const char* __restrict__ Bp,
                   int K, f32x4 (&acc)[2][4]) {
    const int KT = K / 32;
    bool g[2];
    const float* ap[2];
#pragma unroll
    for (int i = 0; i < 2; i++) {
      int row = m0 + sr + i * 32;
      g[i] = row < Mguard;
      ap[i] = A + (size_t)row * K + skc;
    }
    // prologue: tile 0 -> current buf (laggard waves only touch buf^1)
    issueB(Bp, 0, buf);
    {
      float4 a[2];
#pragma unroll
      for (int i = 0; i < 2; i++)
        a[i] = g[i] ? *reinterpret_cast<const float4*>(ap[i]) : make_float4(0.f, 0.f, 0.f, 0.f);
      storeA(a, buf);
    }
    for (int kt = 0; kt < KT; ++kt) {
      __syncthreads();  // drains own glds B(kt) + publishes A_lds[buf]
      // 1) LDS -> fragment registers FIRST (no vm dependence possible)
      bf16x8 ah[2], am[2], al[2];
#pragma unroll
      for (int mt = 0; mt < 2; mt++) {
        const unsigned short* rp = &A_lds[buf][wm * 32 + mt * 16 + l15][0];
        ah[mt] = *reinterpret_cast<const bf16x8*>(rp + quad * 8);
        am[mt] = *reinterpret_cast<const bf16x8*>(rp + 32 + quad * 8);
        al[mt] = *reinterpret_cast<const bf16x8*>(rp + 64 + quad * 8);
      }
      bf16x8 bh[4], bm_[4], bl[4];
#pragma unroll
      for (int nt = 0; nt < 4; nt++) {
        int ln = wn * 64 + nt * 16 + l15;
        int sw = ln & 7;
        const char* rb = &B_lds[buf][(size_t)ln * 128];
        bh[nt]  = *reinterpret_cast<const bf16x8*>(rb + ((quad ^ sw) * 16));
        bm_[nt] = *reinterpret_cast<const bf16x8*>(rb + (((4 + quad) ^ sw) * 16));
        bl[nt]  = *reinterpret_cast<const bf16x8*>(
            &B_lds[buf][16384 + ((size_t)quad * 128 + ln) * 16]);
      }
      // 2) issue next tile's loads (in flight across the MFMA burst)
      const bool pf = (kt + 1 < KT);
      float4 a[2];
      if (pf) {
        issueB(Bp, kt + 1, buf ^ 1);
#pragma unroll
        for (int i = 0; i < 2; i++)
          a[i] = g[i] ? *reinterpret_cast<const float4*>(ap[i] + (kt + 1) * 32)
                      : make_float4(0.f, 0.f, 0.f, 0.f);
      }
      // 3) MFMA burst (order fixed: nt, mt, 6 products)
#pragma unroll
      for (int nt = 0; nt < 4; nt++) {
#pragma unroll
        for (int mt = 0; mt < 2; mt++) {
          acc[mt][nt] = __builtin_amdgcn_mfma_f32_16x16x32_bf16(ah[mt], bh[nt],  acc[mt][nt], 0, 0, 0);
          acc[mt][nt] = __builtin_amdgcn_mfma_f32_16x16x32_bf16(ah[mt], bm_[nt], acc[mt][nt], 0, 0, 0);
          acc[mt][nt] = __builtin_amdgcn_mfma_f32_16x16x32_bf16(am[mt], bh[nt],  acc[mt][nt], 0, 0, 0);
          acc[mt][nt] = __builtin_amdgcn_mfma_f32_16x16x32_bf16(am[mt], bm_[nt], acc[mt][nt], 0, 0, 0);
          acc[mt][nt] = __builtin_amdgcn_mfma_f32_16x16x32_bf16(ah[mt], bl[nt],  acc[mt][nt], 0, 0, 0);
          acc[mt][nt] = __builtin_amdgcn_mfma_f32_16x16x32_bf16(al[mt], bh[nt],  acc[mt][nt], 0, 0, 0);
        }
      }
      // 4) stage next A tile
      if (pf) storeA(a, buf ^ 1);
      buf ^= 1;
    }
  };

  phase(A1, B1, K1, acc1);
  if (A2) phase(A2, B2, K2, acc1);
  if constexpr (GATED) phase(resid, BG, HID, acc2);

  // epilogue. C/D layout: col = lane&15, row = quad*4 + reg  [m89-verified]
#pragma unroll
  for (int nt = 0; nt < 4; nt++) {
    int colc = n0 + wn * 64 + nt * 16 + l15;
    float sc = Sc ? Sc[colc] : 1.0f;
    float tc = Tc[colc];
    float gb = 0.0f;
    if constexpr (GATED) gb = Gb[colc];
#pragma unroll
    for (int mt = 0; mt < 2; mt++) {
#pragma unroll
      for (int r = 0; r < 4; r++) {
        int row = m0 + wm * 32 + mt * 16 + quad * 4 + r;
        size_t base = (size_t)row * Bn + colc;
        float v = acc1[mt][nt][r] * sc + tc;
        if (do_relu) v = fmaxf(v, 0.0f);
        if constexpr (GATED) {
          float p = resid[base];
          float g = 1.0f / (1.0f + __expf(-(acc2[mt][nt][r] + gb)));
          v = g * p + (1.0f - g) * (v + p);
        } else if (resid) {
          v += resid[base];
        }
        C[base] = v;
      }
    }
  }
}

// ---------------- classifier stage 2: [M,128] @ [128,40] + b ----------------
__global__ __launch_bounds__(256)
void classifier2(const float* __restrict__ Tin, const float* __restrict__ W,
                 const float* __restrict__ bias, float* __restrict__ out, int M) {
  __shared__ float Ws[DIN * NCLS];
  __shared__ float bs[NCLS];
  __shared__ float Ts[64][DIN + 4];
  int tid = threadIdx.x;
  for (int i = tid; i < DIN * NCLS; i += 256) Ws[i] = W[i];
  if (tid < NCLS) bs[tid] = bias[tid];
  int row0 = blockIdx.x * 64;
  for (int idx = tid; idx < 64 * (DIN / 4); idx += 256) {
    int r = idx / (DIN / 4);
    int c4 = idx % (DIN / 4);
    float4 v = make_float4(0.f, 0.f, 0.f, 0.f);
    if (row0 + r < M) v = *reinterpret_cast<const float4*>(Tin + (long)(row0 + r) * DIN + c4 * 4);
    *reinterpret_cast<float4*>(&Ts[r][c4 * 4]) = v;
  }
  __syncthreads();
  int r = tid >> 2;
  int c0 = (tid & 3) * 10;
  float s[10];
#pragma unroll
  for (int c = 0; c < 10; c++) s[c] = bs[c0 + c];
  for (int k = 0; k < DIN; k++) {
    float a = Ts[r][k];
#pragma unroll
    for (int c = 0; c < 10; c++) s[c] = fmaf(a, Ws[k * NCLS + c0 + c], s[c]);
  }
  if (row0 + r < M) {
#pragma unroll
    for (int c = 0; c < 10; c++) out[(long)(row0 + r) * NCLS + c0 + c] = s[c];
  }
}

extern "C" void kernel_launch(void* const* d_in, const int* in_sizes, int n_in,
                              void* d_out, int out_size, void* d_ws, size_t ws_size,
                              hipStream_t stream) {
  const float* x      = (const float*)d_in[0];
  const int*   ei     = (const int*)d_in[1];
  const float* Wp     = (const float*)d_in[2];
  const float* bp     = (const float*)d_in[3];
  const float* W1l    = (const float*)d_in[4];
  const float* b1l    = (const float*)d_in[5];
  const float* W1r    = (const float*)d_in[6];
  const float* W2l    = (const float*)d_in[7];
  const float* b2l    = (const float*)d_in[8];
  const float* W2r    = (const float*)d_in[9];
  const float* bn1_g  = (const float*)d_in[10];
  const float* bn1_b  = (const float*)d_in[11];
  const float* bn1_m  = (const float*)d_in[12];
  const float* bn1_v  = (const float*)d_in[13];
  const float* bn2_g  = (const float*)d_in[14];
  const float* bn2_b  = (const float*)d_in[15];
  const float* bn2_m  = (const float*)d_in[16];
  const float* bn2_v  = (const float*)d_in[17];
  const float* gate_W = (const float*)d_in[18];
  const float* gate_b = (const float*)d_in[19];
  const float* Wc1    = (const float*)d_in[20];
  const float* bc1    = (const float*)d_in[21];
  const float* Wc2    = (const float*)d_in[22];
  const float* bc2    = (const float*)d_in[23];
  const int* srcp = ei;
  const int* dstp = ei + NEDGES;

  char* wsb = (char*)d_ws;
  size_t off = 0;
  auto alloc = [&](size_t bytes) -> void* {
    void* p = wsb + off;
    off += (bytes + 255) & ~(size_t)255;
    return p;
  };
  float* X0 = (float*)alloc((size_t)MPAD * HID * 4);
  float* X1 = (float*)alloc((size_t)MPAD * HID * 4);
  float* X2 = (float*)alloc((size_t)MPAD * HID * 4);
  float* X3 = (float*)alloc((size_t)MPAD * HID * 4);
  char* prep = (char*)alloc(5898240);  // 5.9 MB: 16 weight matrices, 3-plane bf16
  int* cnt     = (int*)alloc((size_t)NNODES * 4 * 2);
  int* fillc   = cnt + NNODES;
  int* row_ptr = (int*)alloc((size_t)(NNODES + 1) * 4);
  float* inv   = (float*)alloc((size_t)NNODES * 4);
  int* col     = (int*)alloc((size_t)NEDGES * 4);
  float* S1 = (float*)alloc(NBLK * HID * 4);
  float* T1 = (float*)alloc(NBLK * HID * 4);
  float* S2 = (float*)alloc(NBLK * HID * 4);
  float* T2 = (float*)alloc(NBLK * HID * 4);

  // prep region offsets (bytes). Wp: 4 tiles * 256 * 192 = 196608;
  // 256x256 mats: 8 * 256 * 192 = 393216 each; Wc1: 8 * 128 * 192 = 196608.
  auto poff = [](int idx) -> unsigned {
    if (idx == 0) return 0;
    return 196608u + (unsigned)(idx - 1) * 393216u;
  };
  const char* prepWp  = prep + poff(0);
  auto prepW1l = [&](int i) { return prep + poff(1 + i); };
  auto prepW1r = [&](int i) { return prep + poff(4 + i); };
  auto prepW2l = [&](int i) { return prep + poff(7 + i); };
  auto prepW2r = [&](int i) { return prep + poff(10 + i); };
  auto prepGate = [&](int g) { return prep + poff(13 + g); };
  const char* prepWc1 = prep + poff(15);

  PrepDescs pd;
  {
    int c = 0, k = 0;
    auto add = [&](const float* s, int N, int chunks, unsigned doff) {
      pd.src[k] = s; pd.N[k] = N; c += chunks; pd.cum[k] = c; pd.dst_off[k] = doff; k++;
    };
    add(Wp, 256, 12288, poff(0));                                          // KT=4
    for (int i = 0; i < 3; i++) add(W1l + (size_t)i * 65536, 256, 24576, poff(1 + i));
    for (int i = 0; i < 3; i++) add(W1r + (size_t)i * 65536, 256, 24576, poff(4 + i));
    for (int i = 0; i < 3; i++) add(W2l + (size_t)i * 65536, 256, 24576, poff(7 + i));
    for (int i = 0; i < 3; i++) add(W2r + (size_t)i * 65536, 256, 24576, poff(10 + i));
    for (int g = 0; g < 2; g++) add(gate_W + (size_t)g * 65536, 256, 24576, poff(13 + g));
    add(Wc1, 128, 12288, poff(15));                                        // KT=8,N=128
  }

  hipMemsetAsync(cnt, 0, (size_t)NNODES * 4 * 2, stream);
  int eb = (NEDGES + 255) / 256;
  hist_kernel<<<eb, 256, 0, stream>>>(dstp, cnt, NEDGES);
  scan_kernel<<<1, 1024, 0, stream>>>(cnt, row_ptr, inv, NNODES);
  fill_kernel<<<eb, 256, 0, stream>>>(srcp, dstp, row_ptr, fillc, col, NEDGES);
  fold_kernel<<<3, 256, 0, stream>>>(b1l, bn1_g, bn1_b, bn1_m, bn1_v,
                                     b2l, bn2_g, bn2_b, bn2_m, bn2_v, S1, T1, S2, T2);
  prep_kernel<<<PREP_TOTAL / 256, 256, 0, stream>>>(pd, prep);

  const int gmw = MPAD / 64;     // 782 row-blocks
  const int g256 = gmw * 2;      // Bn=256 grids
  // input projection: X0 = x @ Wp + bp
  gemm_mfma<false><<<g256, 256, 0, stream>>>(
      x, prepWp, DIN, nullptr, nullptr, 0, nullptr, nullptr,
      nullptr, bp, nullptr, X0, 256, NNODES, 0);

  float* bufs[4] = {X0, X1, X2, X3};
  int ip = 0;
  for (int i = 0; i < NBLK; ++i) {
    int im = (ip + 1) & 3;
    int ih = (ip + 2) & 3;
    int id = (ip + 3) & 3;
    float* P  = bufs[ip];
    float* Mb = bufs[im];
    float* Hb = bufs[ih];
    float* Db = bufs[id];
    agg_kernel<<<NNODES, 256, 0, stream>>>(P, Mb, row_ptr, col, inv);
    gemm_mfma<false><<<g256, 256, 0, stream>>>(
        Mb, prepW1l(i), HID, P, prepW1r(i), HID, nullptr, nullptr,
        S1 + i * HID, T1 + i * HID, nullptr, Hb, 256, MPAD, 1);
    agg_kernel<<<NNODES, 256, 0, stream>>>(Hb, Mb, row_ptr, col, inv);
    if (i == 0) {
      gemm_mfma<false><<<g256, 256, 0, stream>>>(
          Mb, prepW2l(0), HID, Hb, prepW2r(0), HID, nullptr, nullptr,
          S2, T2, P, Db, 256, MPAD, 1);
    } else {
      gemm_mfma<true><<<g256, 256, 0, stream>>>(
          Mb, prepW2l(i), HID, Hb, prepW2r(i), HID,
          prepGate(i - 1), gate_b + (size_t)(i - 1) * HID,
          S2 + i * HID, T2 + i * HID, P, Db, 256, MPAD, 1);
    }
    ip = id;
  }
  float* P  = bufs[ip];
  float* Tb = bufs[(ip + 1) & 3];
  gemm_mfma<false><<<gmw, 256, 0, stream>>>(
      P, prepWc1, HID, nullptr, nullptr, 0, nullptr, nullptr,
      nullptr, bc1, nullptr, Tb, 128, MPAD, 1);
  classifier2<<<gmw, 256, 0, stream>>>(Tb, Wc2, bc2, (float*)d_out, NNODES);
}